// Round 1
// baseline (18796.040 us; speedup 1.0000x reference)
//
#include <hip/hip_runtime.h>
#include <hip/hip_bf16.h>

#define LEAKY_SLOPE 0.2f

static inline int cdiv(int a, int b) { return (a + b - 1) / b; }

// ---------------------------------------------------------------------------
// Label representation: char-CNN + relu + max over positions.
// One block (64 threads = 64 output channels) per unique label.
// conv_w[k][i][c] held in registers (80/thread); chars staged in LDS.
// ---------------------------------------------------------------------------
__global__ __launch_bounds__(64) void label_kernel(
    const int* __restrict__ labels, const float* __restrict__ char_embed,
    const float* __restrict__ conv_w, const float* __restrict__ conv_b,
    float* __restrict__ lr, int U)
{
    __shared__ float ch[20][16];   // positions -2..17 (rows 0,1,18,19 are zero pad)
    __shared__ int lab[16];
    const int u = blockIdx.x, t = threadIdx.x;

    {   // zero the 4 pad rows (64 entries)
        const int r = t >> 4, i = t & 15;
        const int padrow[4] = {0, 1, 18, 19};
        ch[padrow[r]][i] = 0.f;
    }
    if (t < 16) lab[t] = labels[(size_t)u * 16 + t];

    float cwr[5][16];
    #pragma unroll
    for (int k = 0; k < 5; ++k)
        #pragma unroll
        for (int i = 0; i < 16; ++i)
            cwr[k][i] = conv_w[(k * 16 + i) * 64 + t];

    __syncthreads();
    for (int j = t; j < 256; j += 64)
        ch[2 + (j >> 4)][j & 15] = char_embed[(size_t)lab[j >> 4] * 16 + (j & 15)];
    __syncthreads();

    float aw[16];
    const float b = conv_b[t];
    #pragma unroll
    for (int w = 0; w < 16; ++w) aw[w] = b;

    #pragma unroll
    for (int x = 0; x < 20; ++x)
        #pragma unroll
        for (int i = 0; i < 16; ++i) {
            const float chv = ch[x][i];
            #pragma unroll
            for (int k = 0; k < 5; ++k) {
                const int w = x - k;
                if (w >= 0 && w < 16) aw[w] += chv * cwr[k][i];
            }
        }
    float m = 0.f;   // relu then max == max(max_w, 0)
    #pragma unroll
    for (int w = 0; w < 16; ++w) m = fmaxf(m, aw[w]);
    lr[(size_t)u * 64 + t] = m;
}

// ---------------------------------------------------------------------------
// h init: h[n][0:64] = label_rep[idx[n]], h[n][64:128] = 0
// ---------------------------------------------------------------------------
__global__ void init_h_kernel(const int* __restrict__ idx,
                              const float* __restrict__ lr,
                              float* __restrict__ h, int N)
{
    const int i = blockIdx.x * blockDim.x + threadIdx.x;
    if (i >= N * 32) return;
    const int n = i >> 5, q = i & 31;
    float4 v = make_float4(0.f, 0.f, 0.f, 0.f);
    if (q < 16)
        v = *reinterpret_cast<const float4*>(lr + (size_t)idx[n] * 64 + (q << 2));
    *reinterpret_cast<float4*>(h + (size_t)n * 128 + (q << 2)) = v;
}

// ---------------------------------------------------------------------------
// Generic fp32 GEMM, K=128 per A/B pair (optionally two pairs summed):
//   C[Mrows x Ncols] = act( A1@B1 (+ A2@B2) + bias )
// Tile 128x128, BK=32, 256 threads, 8x8 micro-tile split 2x(4)+2x(4) to keep
// LDS reads bank-conflict-free. B may be a column slice (ldb row stride).
// C may alias A1 (each block reads only its own rows, writes in epilogue).
// ---------------------------------------------------------------------------
__global__ __launch_bounds__(256) void gemm_k128(
    const float* __restrict__ A1, const float* __restrict__ B1, int ldb1,
    const float* __restrict__ A2, const float* __restrict__ B2, int ldb2,
    const float* __restrict__ bias, float* C,
    int Mrows, int Ncols, int act)
{
    __shared__ float As[32][132];
    __shared__ float Bs[32][132];
    const int tid = threadIdx.x;
    const int tx = tid & 15, ty = tid >> 4;
    const int rowBase = blockIdx.y << 7;
    const int colBase = blockIdx.x << 7;
    const int rowsLeft = Mrows - rowBase;

    float4 acc[2][2][4];
    #pragma unroll
    for (int a = 0; a < 2; ++a)
        #pragma unroll
        for (int c2 = 0; c2 < 2; ++c2)
            #pragma unroll
            for (int i = 0; i < 4; ++i) acc[a][c2][i] = make_float4(0.f, 0.f, 0.f, 0.f);

    const int npass = (A2 != nullptr) ? 2 : 1;
    for (int pass = 0; pass < npass; ++pass) {
        const float* __restrict__ A = pass ? A2 : A1;
        const float* __restrict__ B = pass ? B2 : B1;
        const int ldb = pass ? ldb2 : ldb1;
        #pragma unroll 1
        for (int k0 = 0; k0 < 128; k0 += 32) {
            __syncthreads();
            #pragma unroll
            for (int l = 0; l < 4; ++l) {          // A tile -> transposed LDS
                const int f4 = tid + (l << 8);
                const int row = f4 >> 3, kq = f4 & 7;
                const int gr = row < rowsLeft ? row : 0;
                const float4 av = *reinterpret_cast<const float4*>(
                    A + (size_t)(rowBase + gr) * 128 + k0 + (kq << 2));
                As[(kq << 2) + 0][row] = av.x;
                As[(kq << 2) + 1][row] = av.y;
                As[(kq << 2) + 2][row] = av.z;
                As[(kq << 2) + 3][row] = av.w;
            }
            #pragma unroll
            for (int l = 0; l < 4; ++l) {          // B tile
                const int f4 = tid + (l << 8);
                const int kk = f4 >> 5, cq = f4 & 31;
                *reinterpret_cast<float4*>(&Bs[kk][cq << 2]) =
                    *reinterpret_cast<const float4*>(
                        B + (size_t)(k0 + kk) * ldb + colBase + (cq << 2));
            }
            __syncthreads();
            #pragma unroll
            for (int kk = 0; kk < 32; ++kk) {
                const float4 a0 = *reinterpret_cast<const float4*>(&As[kk][ty << 2]);
                const float4 a1 = *reinterpret_cast<const float4*>(&As[kk][64 + (ty << 2)]);
                const float4 b0 = *reinterpret_cast<const float4*>(&Bs[kk][tx << 2]);
                const float4 b1 = *reinterpret_cast<const float4*>(&Bs[kk][64 + (tx << 2)]);
                const float a0v[4] = {a0.x, a0.y, a0.z, a0.w};
                const float a1v[4] = {a1.x, a1.y, a1.z, a1.w};
                #pragma unroll
                for (int i = 0; i < 4; ++i) {
                    acc[0][0][i].x += a0v[i] * b0.x; acc[0][0][i].y += a0v[i] * b0.y;
                    acc[0][0][i].z += a0v[i] * b0.z; acc[0][0][i].w += a0v[i] * b0.w;
                    acc[0][1][i].x += a0v[i] * b1.x; acc[0][1][i].y += a0v[i] * b1.y;
                    acc[0][1][i].z += a0v[i] * b1.z; acc[0][1][i].w += a0v[i] * b1.w;
                    acc[1][0][i].x += a1v[i] * b0.x; acc[1][0][i].y += a1v[i] * b0.y;
                    acc[1][0][i].z += a1v[i] * b0.z; acc[1][0][i].w += a1v[i] * b0.w;
                    acc[1][1][i].x += a1v[i] * b1.x; acc[1][1][i].y += a1v[i] * b1.y;
                    acc[1][1][i].z += a1v[i] * b1.z; acc[1][1][i].w += a1v[i] * b1.w;
                }
            }
        }
    }
    // epilogue
    #pragma unroll
    for (int rh = 0; rh < 2; ++rh)
        #pragma unroll
        for (int i = 0; i < 4; ++i) {
            const int row = rowBase + (rh << 6) + (ty << 2) + i;
            if (row >= Mrows) continue;
            #pragma unroll
            for (int chh = 0; chh < 2; ++chh) {
                const int col = colBase + (chh << 6) + (tx << 2);
                float4 v = acc[rh][chh][i];
                if (bias) {
                    v.x += bias[col]; v.y += bias[col + 1];
                    v.z += bias[col + 2]; v.w += bias[col + 3];
                }
                if (act == 1) {
                    v.x = v.x > 0.f ? v.x : LEAKY_SLOPE * v.x;
                    v.y = v.y > 0.f ? v.y : LEAKY_SLOPE * v.y;
                    v.z = v.z > 0.f ? v.z : LEAKY_SLOPE * v.z;
                    v.w = v.w > 0.f ? v.w : LEAKY_SLOPE * v.w;
                }
                *reinterpret_cast<float4*>(C + (size_t)row * Ncols + col) = v;
            }
        }
}

// ---------------------------------------------------------------------------
// Edge scatter: agg[tgt] += M[src]  (32 threads/edge, float4 gather + 4 atomics)
// ---------------------------------------------------------------------------
__global__ void scatter_edges(const int* __restrict__ adj, int E,
                              const float* __restrict__ M, float* agg)
{
    const int i = blockIdx.x * blockDim.x + threadIdx.x;
    const int e = i >> 5, q = i & 31;
    if (e >= E) return;
    const int src = adj[2 * e], tgt = adj[2 * e + 1];
    const float4 v = *reinterpret_cast<const float4*>(M + (size_t)src * 128 + (q << 2));
    float* dst = agg + (size_t)tgt * 128 + (q << 2);
    unsafeAtomicAdd(dst + 0, v.x);
    unsafeAtomicAdd(dst + 1, v.y);
    unsafeAtomicAdd(dst + 2, v.z);
    unsafeAtomicAdd(dst + 3, v.w);
}

// ---------------------------------------------------------------------------
// GRU elementwise 1: rh = sigmoid(ZR[:,128:256]) * h   -> written into M
// ---------------------------------------------------------------------------
__global__ void gru_ew1(const float* __restrict__ ZR, const float* __restrict__ h,
                        float* __restrict__ rh, int N)
{
    const int i = blockIdx.x * blockDim.x + threadIdx.x;
    if (i >= N * 32) return;
    const int n = i >> 5, q = i & 31;
    const float4 g = *reinterpret_cast<const float4*>(ZR + (size_t)n * 256 + 128 + (q << 2));
    const float4 hv = *reinterpret_cast<const float4*>(h + (size_t)n * 128 + (q << 2));
    float4 o;
    o.x = hv.x / (1.f + __expf(-g.x));
    o.y = hv.y / (1.f + __expf(-g.y));
    o.z = hv.z / (1.f + __expf(-g.z));
    o.w = hv.w / (1.f + __expf(-g.w));
    *reinterpret_cast<float4*>(rh + (size_t)n * 128 + (q << 2)) = o;
}

// ---------------------------------------------------------------------------
// GRU elementwise 2: h = z*h + (1-z)*tanh(Gh + G3), z = sigmoid(ZR[:, :128])
// ---------------------------------------------------------------------------
__global__ void gru_ew2(const float* __restrict__ ZR, const float* __restrict__ Gh,
                        const float* __restrict__ G3, float* h, int N)
{
    const int i = blockIdx.x * blockDim.x + threadIdx.x;
    if (i >= N * 32) return;
    const int n = i >> 5, q = i & 31;
    const float4 zg = *reinterpret_cast<const float4*>(ZR + (size_t)n * 256 + (q << 2));
    const float4 a = *reinterpret_cast<const float4*>(Gh + (size_t)n * 128 + (q << 2));
    const float4 b = *reinterpret_cast<const float4*>(G3 + (size_t)n * 128 + (q << 2));
    float4 hv = *reinterpret_cast<float4*>(h + (size_t)n * 128 + (q << 2));
    const float zx = 1.f / (1.f + __expf(-zg.x));
    const float zy = 1.f / (1.f + __expf(-zg.y));
    const float zz = 1.f / (1.f + __expf(-zg.z));
    const float zw = 1.f / (1.f + __expf(-zg.w));
    hv.x = zx * hv.x + (1.f - zx) * tanhf(a.x + b.x);
    hv.y = zy * hv.y + (1.f - zy) * tanhf(a.y + b.y);
    hv.z = zz * hv.z + (1.f - zz) * tanhf(a.z + b.z);
    hv.w = zw * hv.w + (1.f - zw) * tanhf(a.w + b.w);
    *reinterpret_cast<float4*>(h + (size_t)n * 128 + (q << 2)) = hv;
}

// ---------------------------------------------------------------------------
// Final: per-node score=sigmoid(h.score_w+b), v = mlp(V1), out[g] += score*v
// One wave per node; small weights staged in LDS.
// ---------------------------------------------------------------------------
__global__ __launch_bounds__(256) void final_kernel(
    const float* __restrict__ h, const float* __restrict__ V1,
    const int* __restrict__ n2g,
    const float* __restrict__ w2, const float* __restrict__ b2,
    const float* __restrict__ w3, const float* __restrict__ b3,
    const float* __restrict__ w4, const float* __restrict__ b4,
    const float* __restrict__ score_w, const float* __restrict__ score_b,
    float* out, int N)
{
    __shared__ float sw2[4096];
    __shared__ float sw3[256];
    __shared__ float ssw[128];
    __shared__ float sb2[32], sb3[8], sw4v[8];
    __shared__ float sb4, ssb;
    __shared__ float v1L[4][128];
    __shared__ float v2L[4][32];
    __shared__ float v3L[4][8];
    const int tid = threadIdx.x;
    for (int i = tid; i < 4096; i += 256) sw2[i] = w2[i];
    sw3[tid] = w3[tid];                 // 256 == blockDim
    if (tid < 128) ssw[tid] = score_w[tid];
    if (tid < 32) sb2[tid] = b2[tid];
    if (tid < 8) { sb3[tid] = b3[tid]; sw4v[tid] = w4[tid]; }
    if (tid == 0) { sb4 = b4[0]; ssb = score_b[0]; }
    __syncthreads();

    const int wave = tid >> 6, lane = tid & 63;
    for (int n = (blockIdx.x << 2) + wave; n < N; n += (gridDim.x << 2)) {
        const float2 hv = *reinterpret_cast<const float2*>(h + (size_t)n * 128 + (lane << 1));
        const float2 v1 = *reinterpret_cast<const float2*>(V1 + (size_t)n * 128 + (lane << 1));
        float sp = hv.x * ssw[lane << 1] + hv.y * ssw[(lane << 1) + 1];
        #pragma unroll
        for (int d = 32; d > 0; d >>= 1) sp += __shfl_xor(sp, d, 64);
        v1L[wave][lane << 1] = v1.x;
        v1L[wave][(lane << 1) + 1] = v1.y;
        asm volatile("s_waitcnt lgkmcnt(0)" ::: "memory");
        if (lane < 32) {
            float o2 = sb2[lane];
            #pragma unroll 8
            for (int k = 0; k < 128; ++k) o2 += v1L[wave][k] * sw2[(k << 5) + lane];
            v2L[wave][lane] = o2 > 0.f ? o2 : LEAKY_SLOPE * o2;
        }
        asm volatile("s_waitcnt lgkmcnt(0)" ::: "memory");
        if (lane < 8) {
            float o3 = sb3[lane];
            #pragma unroll
            for (int k = 0; k < 32; ++k) o3 += v2L[wave][k] * sw3[(k << 3) + lane];
            v3L[wave][lane] = o3 > 0.f ? o3 : LEAKY_SLOPE * o3;
        }
        asm volatile("s_waitcnt lgkmcnt(0)" ::: "memory");
        if (lane == 0) {
            float o4 = sb4;
            #pragma unroll
            for (int k = 0; k < 8; ++k) o4 += v3L[wave][k] * sw4v[k];
            const float sc = 1.f / (1.f + __expf(-(sp + ssb)));
            unsafeAtomicAdd(out + n2g[n], sc * o4);
        }
    }
}

// ---------------------------------------------------------------------------
extern "C" void kernel_launch(void* const* d_in, const int* in_sizes, int n_in,
                              void* d_out, int out_size, void* d_ws, size_t ws_size,
                              hipStream_t stream)
{
    (void)n_in;
    const int* labels   = (const int*)d_in[1];
    const int* nidx     = (const int*)d_in[2];
    const int* n2g      = (const int*)d_in[3];
    const int* adj[12]; int Ecnt[12];
    for (int t = 0; t < 12; ++t) { adj[t] = (const int*)d_in[5 + t]; Ecnt[t] = in_sizes[5 + t] / 2; }
    const float* char_embed = (const float*)d_in[17];
    const float* conv_w     = (const float*)d_in[18];
    const float* conv_b     = (const float*)d_in[19];
    const float* W_msg      = (const float*)d_in[20];
    const float* gru_k      = (const float*)d_in[21];
    const float* gru_rk     = (const float*)d_in[22];
    const float* gru_b      = (const float*)d_in[23];
    const float* score_w    = (const float*)d_in[24];
    const float* score_b    = (const float*)d_in[25];
    const float* w1 = (const float*)d_in[26];
    const float* b1 = (const float*)d_in[27];
    const float* w2 = (const float*)d_in[28];
    const float* b2 = (const float*)d_in[29];
    const float* w3 = (const float*)d_in[30];
    const float* b3 = (const float*)d_in[31];
    const float* w4 = (const float*)d_in[32];
    const float* b4 = (const float*)d_in[33];

    const int N = in_sizes[2];
    const int U = in_sizes[1] / 16;
    const int G = out_size;
    float* out = (float*)d_out;

    float* ws = (float*)d_ws;
    size_t o = 0;
    float* lr  = ws + o; o += (size_t)U * 64;
    float* h   = ws + o; o += (size_t)N * 128;
    float* agg = ws + o; o += (size_t)N * 128;
    float* M   = ws + o; o += (size_t)N * 128;
    float* ZR  = ws + o; o += (size_t)N * 256;
    if (o * sizeof(float) > ws_size) return;   // workspace too small: bail (clean failure signal)

    hipMemsetAsync(d_out, 0, (size_t)G * sizeof(float), stream);
    label_kernel<<<U, 64, 0, stream>>>(labels, char_embed, conv_w, conv_b, lr, U);
    init_h_kernel<<<cdiv(N * 32, 256), 256, 0, stream>>>(nidx, lr, h, N);

    const dim3 g1(1, cdiv(N, 128)), g2(2, cdiv(N, 128));
    for (int layer = 0; layer < 6; ++layer) {
        hipMemsetAsync(agg, 0, (size_t)N * 128 * sizeof(float), stream);
        const float* kl  = gru_k  + (size_t)layer * 128 * 384;
        const float* rkl = gru_rk + (size_t)layer * 128 * 384;
        const float* bl  = gru_b  + (size_t)layer * 384;
        for (int t = 0; t < 12; ++t) {
            const float* Wt = W_msg + ((size_t)layer * 12 + t) * 128 * 128;
            gemm_k128<<<g1, 256, 0, stream>>>(h, Wt, 128, nullptr, nullptr, 0,
                                              nullptr, M, N, 128, 0);
            scatter_edges<<<cdiv(Ecnt[t] * 32, 256), 256, 0, stream>>>(adj[t], Ecnt[t], M, agg);
        }
        // ZR = agg@k[:, :256] + h@rk[:, :256] + b[:256]
        gemm_k128<<<g2, 256, 0, stream>>>(agg, kl, 384, h, rkl, 384, bl, ZR, N, 256, 0);
        // Gh (in-place): agg = agg@k[:, 256:384] + b[256:]
        gemm_k128<<<g1, 256, 0, stream>>>(agg, kl + 256, 384, nullptr, nullptr, 0,
                                          bl + 256, agg, N, 128, 0);
        // rh = sigmoid(r) * h  -> M
        gru_ew1<<<cdiv(N * 32, 256), 256, 0, stream>>>(ZR, h, M, N);
        // G3 (in-place): M = M @ rk[:, 256:384]
        gemm_k128<<<g1, 256, 0, stream>>>(M, rkl + 256, 384, nullptr, nullptr, 0,
                                          nullptr, M, N, 128, 0);
        // h = z*h + (1-z)*tanh(Gh + G3)
        gru_ew2<<<cdiv(N * 32, 256), 256, 0, stream>>>(ZR, agg, M, h, N);
    }
    // V1 = leaky(h @ w1 + b1) -> M
    gemm_k128<<<g1, 256, 0, stream>>>(h, w1, 128, nullptr, nullptr, 0, b1, M, N, 128, 1);
    final_kernel<<<512, 256, 0, stream>>>(h, M, n2g, w2, b2, w3, b3, w4, b4,
                                          score_w, score_b, out, N);
}

// Round 3
// 7927.083 us; speedup vs baseline: 2.3711x; 2.3711x over previous
//
#include <hip/hip_runtime.h>
#include <hip/hip_bf16.h>

#define LEAKY_SLOPE 0.2f

static inline int cdiv(int a, int b) { return (a + b - 1) / b; }

struct EdgeArgs {
    const int* adj[12];
    int E[12];
    int colOff[12];
};

// ---------------------------------------------------------------------------
// Label representation: char-CNN + relu + max over positions.
// One block (64 threads = 64 output channels) per unique label.
// ---------------------------------------------------------------------------
__global__ __launch_bounds__(64) void label_kernel(
    const int* __restrict__ labels, const float* __restrict__ char_embed,
    const float* __restrict__ conv_w, const float* __restrict__ conv_b,
    float* __restrict__ lr, int U)
{
    __shared__ float ch[20][16];   // positions -2..17 (rows 0,1,18,19 are zero pad)
    __shared__ int lab[16];
    const int u = blockIdx.x, t = threadIdx.x;

    {   // zero the 4 pad rows (64 entries)
        const int r = t >> 4, i = t & 15;
        const int padrow[4] = {0, 1, 18, 19};
        ch[padrow[r]][i] = 0.f;
    }
    if (t < 16) lab[t] = labels[(size_t)u * 16 + t];

    float cwr[5][16];
    #pragma unroll
    for (int k = 0; k < 5; ++k)
        #pragma unroll
        for (int i = 0; i < 16; ++i)
            cwr[k][i] = conv_w[(k * 16 + i) * 64 + t];

    __syncthreads();
    for (int j = t; j < 256; j += 64)
        ch[2 + (j >> 4)][j & 15] = char_embed[(size_t)lab[j >> 4] * 16 + (j & 15)];
    __syncthreads();

    float aw[16];
    const float b = conv_b[t];
    #pragma unroll
    for (int w = 0; w < 16; ++w) aw[w] = b;

    #pragma unroll
    for (int x = 0; x < 20; ++x)
        #pragma unroll
        for (int i = 0; i < 16; ++i) {
            const float chv = ch[x][i];
            #pragma unroll
            for (int k = 0; k < 5; ++k) {
                const int w = x - k;
                if (w >= 0 && w < 16) aw[w] += chv * cwr[k][i];
            }
        }
    float m = 0.f;   // relu then max == max(max_w, 0)
    #pragma unroll
    for (int w = 0; w < 16; ++w) m = fmaxf(m, aw[w]);
    lr[(size_t)u * 64 + t] = m;
}

// ---------------------------------------------------------------------------
// h init: h[n][0:64] = label_rep[idx[n]], h[n][64:128] = 0
// ---------------------------------------------------------------------------
__global__ void init_h_kernel(const int* __restrict__ idx,
                              const float* __restrict__ lr,
                              float* __restrict__ h, int N)
{
    const int i = blockIdx.x * blockDim.x + threadIdx.x;
    if (i >= N * 32) return;
    const int n = i >> 5, q = i & 31;
    float4 v = make_float4(0.f, 0.f, 0.f, 0.f);
    if (q < 16)
        v = *reinterpret_cast<const float4*>(lr + (size_t)idx[n] * 64 + (q << 2));
    *reinterpret_cast<float4*>(h + (size_t)n * 128 + (q << 2)) = v;
}

// ---------------------------------------------------------------------------
// CSR build: histogram of tgt -> per-etype exclusive scan -> slot fill.
// ---------------------------------------------------------------------------
__global__ void hist_kernel(EdgeArgs ea, int* __restrict__ deg, int N)
{
    const int t = blockIdx.y;
    const int e = blockIdx.x * blockDim.x + threadIdx.x;
    if (e >= ea.E[t]) return;
    atomicAdd(&deg[(size_t)t * N + ea.adj[t][2 * e + 1]], 1);
}

__global__ __launch_bounds__(256) void scan_kernel(const int* __restrict__ deg,
                                                   int* __restrict__ rowptr, int N)
{
    const int t = blockIdx.x;
    const int* d = deg + (size_t)t * N;
    int* rp = rowptr + (size_t)t * (N + 1);
    __shared__ int ts[256];
    __shared__ int carrySh;
    if (threadIdx.x == 0) { carrySh = 0; rp[0] = 0; }
    __syncthreads();
    for (int base = 0; base < N; base += 2048) {
        int v[8]; int s = 0;
        #pragma unroll
        for (int j = 0; j < 8; ++j) {
            const int i = base + threadIdx.x * 8 + j;
            v[j] = (i < N) ? d[i] : 0;
            s += v[j];
        }
        ts[threadIdx.x] = s;
        __syncthreads();
        for (int off = 1; off < 256; off <<= 1) {
            const int val = (threadIdx.x >= off) ? ts[threadIdx.x - off] : 0;
            __syncthreads();
            ts[threadIdx.x] += val;
            __syncthreads();
        }
        int run = carrySh + (threadIdx.x ? ts[threadIdx.x - 1] : 0);
        #pragma unroll
        for (int j = 0; j < 8; ++j) {
            const int i = base + threadIdx.x * 8 + j;
            run += v[j];
            if (i < N) rp[i + 1] = run;
        }
        __syncthreads();
        if (threadIdx.x == 255) carrySh += ts[255];
        __syncthreads();
    }
}

__global__ void fill_kernel(EdgeArgs ea, const int* __restrict__ rowptr,
                            int* __restrict__ cursor, int* __restrict__ col, int N)
{
    const int t = blockIdx.y;
    const int e = blockIdx.x * blockDim.x + threadIdx.x;
    if (e >= ea.E[t]) return;
    const int s  = ea.adj[t][2 * e];
    const int tg = ea.adj[t][2 * e + 1];
    const int pos = rowptr[(size_t)t * (N + 1) + tg] + atomicAdd(&cursor[(size_t)t * N + tg], 1);
    col[ea.colOff[t] + pos] = s;
}

// ---------------------------------------------------------------------------
// CSR gather: agg[n] (+)= sum_{src in in-edges(n)} M[src]. 32 threads/node.
// Atomic-free: each agg row written exactly once per dispatch.
// ---------------------------------------------------------------------------
__global__ __launch_bounds__(256) void gather_csr(
    const int* __restrict__ rowptr, const int* __restrict__ col,
    const float* __restrict__ M, float* __restrict__ agg, int N, int accum)
{
    const int i = blockIdx.x * blockDim.x + threadIdx.x;
    const int n = i >> 5, q = i & 31;
    if (n >= N) return;
    int s = rowptr[n];
    const int e = rowptr[n + 1];
    float4 acc;
    if (accum) acc = *reinterpret_cast<const float4*>(agg + (size_t)n * 128 + (q << 2));
    else       acc = make_float4(0.f, 0.f, 0.f, 0.f);
    for (; s < e; ++s) {
        const int src = col[s];
        const float4 v = *reinterpret_cast<const float4*>(M + (size_t)src * 128 + (q << 2));
        acc.x += v.x; acc.y += v.y; acc.z += v.z; acc.w += v.w;
    }
    *reinterpret_cast<float4*>(agg + (size_t)n * 128 + (q << 2)) = acc;
}

// ---------------------------------------------------------------------------
// Generic fp32 GEMM, K=128 per A/B pair (optionally two pairs summed):
//   C = act( A1@B1 (+ A2@B2) + bias ),  acts: 0 none, 1 leaky-relu,
//   2 sigmoid, 3 sigmoid * hmul[row] (row-wise gate fusion).
// Tile 128x128, BK=32, 256 threads, 8x8 micro-tile. C may alias A1
// (each block reads only its own C-rows before writing in epilogue).
// ---------------------------------------------------------------------------
__global__ __launch_bounds__(256) void gemm_k128(
    const float* __restrict__ A1, const float* __restrict__ B1, int ldb1,
    const float* __restrict__ A2, const float* __restrict__ B2, int ldb2,
    const float* __restrict__ bias, const float* __restrict__ hmul,
    float* C, int Mrows, int Ncols, int act)
{
    __shared__ float As[32][132];
    __shared__ float Bs[32][132];
    const int tid = threadIdx.x;
    const int tx = tid & 15, ty = tid >> 4;
    const int rowBase = blockIdx.y << 7;
    const int colBase = blockIdx.x << 7;
    const int rowsLeft = Mrows - rowBase;

    float4 acc[2][2][4];
    #pragma unroll
    for (int a = 0; a < 2; ++a)
        #pragma unroll
        for (int c2 = 0; c2 < 2; ++c2)
            #pragma unroll
            for (int i = 0; i < 4; ++i) acc[a][c2][i] = make_float4(0.f, 0.f, 0.f, 0.f);

    const int npass = (A2 != nullptr) ? 2 : 1;
    for (int pass = 0; pass < npass; ++pass) {
        const float* __restrict__ A = pass ? A2 : A1;
        const float* __restrict__ B = pass ? B2 : B1;
        const int ldb = pass ? ldb2 : ldb1;
        #pragma unroll 1
        for (int k0 = 0; k0 < 128; k0 += 32) {
            __syncthreads();
            #pragma unroll
            for (int l = 0; l < 4; ++l) {          // A tile -> transposed LDS
                const int f4 = tid + (l << 8);
                const int row = f4 >> 3, kq = f4 & 7;
                const int gr = row < rowsLeft ? row : 0;
                const float4 av = *reinterpret_cast<const float4*>(
                    A + (size_t)(rowBase + gr) * 128 + k0 + (kq << 2));
                As[(kq << 2) + 0][row] = av.x;
                As[(kq << 2) + 1][row] = av.y;
                As[(kq << 2) + 2][row] = av.z;
                As[(kq << 2) + 3][row] = av.w;
            }
            #pragma unroll
            for (int l = 0; l < 4; ++l) {          // B tile
                const int f4 = tid + (l << 8);
                const int kk = f4 >> 5, cq = f4 & 31;
                *reinterpret_cast<float4*>(&Bs[kk][cq << 2]) =
                    *reinterpret_cast<const float4*>(
                        B + (size_t)(k0 + kk) * ldb + colBase + (cq << 2));
            }
            __syncthreads();
            #pragma unroll
            for (int kk = 0; kk < 32; ++kk) {
                const float4 a0 = *reinterpret_cast<const float4*>(&As[kk][ty << 2]);
                const float4 a1 = *reinterpret_cast<const float4*>(&As[kk][64 + (ty << 2)]);
                const float4 b0 = *reinterpret_cast<const float4*>(&Bs[kk][tx << 2]);
                const float4 b1 = *reinterpret_cast<const float4*>(&Bs[kk][64 + (tx << 2)]);
                const float a0v[4] = {a0.x, a0.y, a0.z, a0.w};
                const float a1v[4] = {a1.x, a1.y, a1.z, a1.w};
                #pragma unroll
                for (int i = 0; i < 4; ++i) {
                    acc[0][0][i].x += a0v[i] * b0.x; acc[0][0][i].y += a0v[i] * b0.y;
                    acc[0][0][i].z += a0v[i] * b0.z; acc[0][0][i].w += a0v[i] * b0.w;
                    acc[0][1][i].x += a0v[i] * b1.x; acc[0][1][i].y += a0v[i] * b1.y;
                    acc[0][1][i].z += a0v[i] * b1.z; acc[0][1][i].w += a0v[i] * b1.w;
                    acc[1][0][i].x += a1v[i] * b0.x; acc[1][0][i].y += a1v[i] * b0.y;
                    acc[1][0][i].z += a1v[i] * b0.z; acc[1][0][i].w += a1v[i] * b0.w;
                    acc[1][1][i].x += a1v[i] * b1.x; acc[1][1][i].y += a1v[i] * b1.y;
                    acc[1][1][i].z += a1v[i] * b1.z; acc[1][1][i].w += a1v[i] * b1.w;
                }
            }
        }
    }
    // epilogue
    #pragma unroll
    for (int rh = 0; rh < 2; ++rh)
        #pragma unroll
        for (int i = 0; i < 4; ++i) {
            const int row = rowBase + (rh << 6) + (ty << 2) + i;
            if (row >= Mrows) continue;
            #pragma unroll
            for (int chh = 0; chh < 2; ++chh) {
                const int col = colBase + (chh << 6) + (tx << 2);
                float4 v = acc[rh][chh][i];
                if (bias) {
                    v.x += bias[col]; v.y += bias[col + 1];
                    v.z += bias[col + 2]; v.w += bias[col + 3];
                }
                if (act == 1) {
                    v.x = v.x > 0.f ? v.x : LEAKY_SLOPE * v.x;
                    v.y = v.y > 0.f ? v.y : LEAKY_SLOPE * v.y;
                    v.z = v.z > 0.f ? v.z : LEAKY_SLOPE * v.z;
                    v.w = v.w > 0.f ? v.w : LEAKY_SLOPE * v.w;
                } else if (act >= 2) {
                    v.x = 1.f / (1.f + __expf(-v.x));
                    v.y = 1.f / (1.f + __expf(-v.y));
                    v.z = 1.f / (1.f + __expf(-v.z));
                    v.w = 1.f / (1.f + __expf(-v.w));
                    if (act == 3) {
                        const float4 hm = *reinterpret_cast<const float4*>(
                            hmul + (size_t)row * 128 + col);
                        v.x *= hm.x; v.y *= hm.y; v.z *= hm.z; v.w *= hm.w;
                    }
                }
                *reinterpret_cast<float4*>(C + (size_t)row * Ncols + col) = v;
            }
        }
}

// ---------------------------------------------------------------------------
// GRU final elementwise: h = Z*h + (1-Z)*tanh(Gh + G3); Z pre-sigmoided.
// ---------------------------------------------------------------------------
__global__ void gru_ew2(const float* __restrict__ Z, const float* __restrict__ Gh,
                        const float* __restrict__ G3, float* h, int N)
{
    const int i = blockIdx.x * blockDim.x + threadIdx.x;
    if (i >= N * 32) return;
    const int n = i >> 5, q = i & 31;
    const float4 z = *reinterpret_cast<const float4*>(Z + (size_t)n * 128 + (q << 2));
    const float4 a = *reinterpret_cast<const float4*>(Gh + (size_t)n * 128 + (q << 2));
    const float4 b = *reinterpret_cast<const float4*>(G3 + (size_t)n * 128 + (q << 2));
    float4 hv = *reinterpret_cast<float4*>(h + (size_t)n * 128 + (q << 2));
    hv.x = z.x * hv.x + (1.f - z.x) * tanhf(a.x + b.x);
    hv.y = z.y * hv.y + (1.f - z.y) * tanhf(a.y + b.y);
    hv.z = z.z * hv.z + (1.f - z.z) * tanhf(a.z + b.z);
    hv.w = z.w * hv.w + (1.f - z.w) * tanhf(a.w + b.w);
    *reinterpret_cast<float4*>(h + (size_t)n * 128 + (q << 2)) = hv;
}

// ---------------------------------------------------------------------------
// Final: thread-per-node. Weights read with wave-uniform indices (compiler
// scalarizes to s_load). n2g is sorted -> most waves are graph-uniform:
// butterfly-reduce and emit ONE atomic per wave.
// ---------------------------------------------------------------------------
__global__ __launch_bounds__(256) void final_kernel(
    const float* __restrict__ h, const float* __restrict__ V1,
    const int* __restrict__ n2g,
    const float* __restrict__ w2, const float* __restrict__ b2,
    const float* __restrict__ w3, const float* __restrict__ b3,
    const float* __restrict__ w4, const float* __restrict__ b4,
    const float* __restrict__ score_w, const float* __restrict__ score_b,
    float* __restrict__ out, int N)
{
    const int n = blockIdx.x * blockDim.x + threadIdx.x;
    const int nc = n < N ? n : N - 1;           // clamp: pads read valid memory
    const int g = n2g[nc];

    float V2[32];
    #pragma unroll
    for (int j = 0; j < 32; ++j) V2[j] = b2[j];
    float sp = score_b[0];

    #pragma unroll 2
    for (int k = 0; k < 128; k += 4) {
        const float4 v1 = *reinterpret_cast<const float4*>(V1 + (size_t)nc * 128 + k);
        const float4 hv = *reinterpret_cast<const float4*>(h  + (size_t)nc * 128 + k);
        sp += hv.x * score_w[k] + hv.y * score_w[k + 1]
            + hv.z * score_w[k + 2] + hv.w * score_w[k + 3];
        const float vv[4] = {v1.x, v1.y, v1.z, v1.w};
        #pragma unroll
        for (int kk = 0; kk < 4; ++kk)
            #pragma unroll
            for (int j = 0; j < 32; ++j)
                V2[j] += vv[kk] * w2[(k + kk) * 32 + j];
    }
    #pragma unroll
    for (int j = 0; j < 32; ++j) { const float x = V2[j]; V2[j] = x > 0.f ? x : LEAKY_SLOPE * x; }

    float V3[8];
    #pragma unroll
    for (int j = 0; j < 8; ++j) V3[j] = b3[j];
    #pragma unroll
    for (int k = 0; k < 32; ++k)
        #pragma unroll
        for (int j = 0; j < 8; ++j) V3[j] += V2[k] * w3[k * 8 + j];
    #pragma unroll
    for (int j = 0; j < 8; ++j) { const float x = V3[j]; V3[j] = x > 0.f ? x : LEAKY_SLOPE * x; }

    float o4 = b4[0];
    #pragma unroll
    for (int j = 0; j < 8; ++j) o4 += V3[j] * w4[j];

    const float sc = 1.f / (1.f + __expf(-sp));
    float val = (n < N) ? sc * o4 : 0.f;

    const int g0 = __shfl(g, 0, 64);
    if (__all(g == g0)) {
        #pragma unroll
        for (int d = 32; d > 0; d >>= 1) val += __shfl_xor(val, d, 64);
        if ((threadIdx.x & 63) == 0) unsafeAtomicAdd(out + g0, val);
    } else {
        if (n < N) unsafeAtomicAdd(out + g, val);
    }
}

// ---------------------------------------------------------------------------
extern "C" void kernel_launch(void* const* d_in, const int* in_sizes, int n_in,
                              void* d_out, int out_size, void* d_ws, size_t ws_size,
                              hipStream_t stream)
{
    (void)n_in;
    const int* labels   = (const int*)d_in[1];
    const int* nidx     = (const int*)d_in[2];
    const int* n2g      = (const int*)d_in[3];
    EdgeArgs ea;
    int Emax = 0, Etot = 0;
    for (int t = 0; t < 12; ++t) {
        ea.adj[t] = (const int*)d_in[5 + t];
        ea.E[t] = in_sizes[5 + t] / 2;
        ea.colOff[t] = Etot;
        Etot += ea.E[t];
        if (ea.E[t] > Emax) Emax = ea.E[t];
    }
    const float* char_embed = (const float*)d_in[17];
    const float* conv_w     = (const float*)d_in[18];
    const float* conv_b     = (const float*)d_in[19];
    const float* W_msg      = (const float*)d_in[20];
    const float* gru_k      = (const float*)d_in[21];
    const float* gru_rk     = (const float*)d_in[22];
    const float* gru_b      = (const float*)d_in[23];
    const float* score_w    = (const float*)d_in[24];
    const float* score_b    = (const float*)d_in[25];
    const float* w1 = (const float*)d_in[26];
    const float* b1 = (const float*)d_in[27];
    const float* w2 = (const float*)d_in[28];
    const float* b2 = (const float*)d_in[29];
    const float* w3 = (const float*)d_in[30];
    const float* b3 = (const float*)d_in[31];
    const float* w4 = (const float*)d_in[32];
    const float* b4 = (const float*)d_in[33];

    const int N = in_sizes[2];
    const int U = in_sizes[1] / 16;
    const int G = out_size;
    float* out = (float*)d_out;

    // ---- workspace layout (keep total WELL below the ~261MB known-good) ----
    float* ws = (float*)d_ws;
    size_t o = 0;
    float* lr  = ws + o; o += (size_t)U * 64;
    float* h   = ws + o; o += (size_t)N * 128;
    float* agg = ws + o; o += (size_t)N * 128;
    float* M   = ws + o; o += (size_t)N * 128;
    float* Z   = ws + o; o += (size_t)N * 128;
    int* rowptr = (int*)(ws + o);                    // persists all layers
    int* colarr = rowptr + (size_t)12 * (N + 1);
    const size_t total_bytes = o * sizeof(float)
        + ((size_t)12 * (N + 1) + (size_t)Etot) * sizeof(int);
    if (total_bytes > ws_size) return;               // clean failure signal

    // CSR-build temporaries live inside M (free until layer 0's first GEMM)
    int* deg    = (int*)M;
    int* cursor = deg + (size_t)12 * N;              // 24N ints = 9.6MB << 51.2MB

    hipMemsetAsync(d_out, 0, (size_t)G * sizeof(float), stream);
    hipMemsetAsync(deg, 0, (size_t)24 * N * sizeof(int), stream);

    // ---- CSR build (graph is layer-invariant) ----
    {
        const dim3 ge(cdiv(Emax, 256), 12);
        hist_kernel<<<ge, 256, 0, stream>>>(ea, deg, N);
        scan_kernel<<<12, 256, 0, stream>>>(deg, rowptr, N);
        fill_kernel<<<ge, 256, 0, stream>>>(ea, rowptr, cursor, colarr, N);
    }

    label_kernel<<<U, 64, 0, stream>>>(labels, char_embed, conv_w, conv_b, lr, U);
    init_h_kernel<<<cdiv(N * 32, 256), 256, 0, stream>>>(nidx, lr, h, N);

    const dim3 g1(1, cdiv(N, 128));
    const int gatherBlocks = cdiv(N * 32, 256);
    for (int layer = 0; layer < 6; ++layer) {
        const float* kl  = gru_k  + (size_t)layer * 128 * 384;
        const float* rkl = gru_rk + (size_t)layer * 128 * 384;
        const float* bl  = gru_b  + (size_t)layer * 384;
        for (int t = 0; t < 12; ++t) {
            const float* Wt = W_msg + ((size_t)layer * 12 + t) * 128 * 128;
            gemm_k128<<<g1, 256, 0, stream>>>(h, Wt, 128, nullptr, nullptr, 0,
                                              nullptr, nullptr, M, N, 128, 0);
            gather_csr<<<gatherBlocks, 256, 0, stream>>>(
                rowptr + (size_t)t * (N + 1), colarr + ea.colOff[t], M, agg, N, t > 0);
        }
        // Z = sigmoid(agg@k[:, :128] + h@rk[:, :128] + b[:128])
        gemm_k128<<<g1, 256, 0, stream>>>(agg, kl, 384, h, rkl, 384,
                                          bl, nullptr, Z, N, 128, 2);
        // rh = sigmoid(agg@k[:,128:256] + h@rk[:,128:256] + b[128:256]) * h -> M
        gemm_k128<<<g1, 256, 0, stream>>>(agg, kl + 128, 384, h, rkl + 128, 384,
                                          bl + 128, h, M, N, 128, 3);
        // Gh (in-place): agg = agg@k[:, 256:384] + b[256:]
        gemm_k128<<<g1, 256, 0, stream>>>(agg, kl + 256, 384, nullptr, nullptr, 0,
                                          bl + 256, nullptr, agg, N, 128, 0);
        // G3 (in-place): M = M @ rk[:, 256:384]
        gemm_k128<<<g1, 256, 0, stream>>>(M, rkl + 256, 384, nullptr, nullptr, 0,
                                          nullptr, nullptr, M, N, 128, 0);
        // h = Z*h + (1-Z)*tanh(Gh + G3)
        gru_ew2<<<cdiv(N * 32, 256), 256, 0, stream>>>(Z, agg, M, h, N);
    }
    // V1 = leaky(h @ w1 + b1) -> M
    gemm_k128<<<g1, 256, 0, stream>>>(h, w1, 128, nullptr, nullptr, 0,
                                      b1, nullptr, M, N, 128, 1);
    final_kernel<<<cdiv(N, 256), 256, 0, stream>>>(h, M, n2g, w2, b2, w3, b3, w4, b4,
                                                   score_w, score_b, out, N);
}

// Round 4
// 5973.894 us; speedup vs baseline: 3.1464x; 1.3270x over previous
//
#include <hip/hip_runtime.h>
#include <hip/hip_bf16.h>

#define LEAKY_SLOPE 0.2f

typedef short short8 __attribute__((ext_vector_type(8)));
typedef float f32x4 __attribute__((ext_vector_type(4)));

static inline int cdiv(int a, int b) { return (a + b - 1) / b; }

// ---- bf16 split helpers (RNE) ------------------------------------------------
__device__ inline float bf2f(unsigned short s) {
    return __uint_as_float(((unsigned int)s) << 16);
}
__device__ inline unsigned short f2bf(float x) {
    unsigned int u = __float_as_uint(x);
    return (unsigned short)((u + 0x7FFFu + ((u >> 16) & 1u)) >> 16);
}
__device__ inline unsigned short bf_hi(float x, float& rem) {
    unsigned int u = __float_as_uint(x);
    unsigned int hi = (u + 0x7FFFu + ((u >> 16) & 1u)) & 0xFFFF0000u;
    rem = x - __uint_as_float(hi);
    return (unsigned short)(hi >> 16);
}
// split-tiled addressing: element (row r, feature k) of an N x 128 matrix lives
// at unit  panel*32768 + (k>>3)*1024 + (r&127)*8 + (k&7); lo plane at +16384.
__device__ inline size_t tileu(int r, int k) {
    return (size_t)(r >> 7) * 32768 + (size_t)(k >> 3) * 1024 + (size_t)(r & 127) * 8 + (k & 7);
}

struct EdgeArgs {
    const int* adj[12];
    int E[12];
    int colOff[12];
};

// ---------------------------------------------------------------------------
// Label representation: char-CNN + relu + max over positions.
// ---------------------------------------------------------------------------
__global__ __launch_bounds__(64) void label_kernel(
    const int* __restrict__ labels, const float* __restrict__ char_embed,
    const float* __restrict__ conv_w, const float* __restrict__ conv_b,
    float* __restrict__ lr, int U)
{
    __shared__ float ch[20][16];
    __shared__ int lab[16];
    const int u = blockIdx.x, t = threadIdx.x;
    {
        const int r = t >> 4, i = t & 15;
        const int padrow[4] = {0, 1, 18, 19};
        ch[padrow[r]][i] = 0.f;
    }
    if (t < 16) lab[t] = labels[(size_t)u * 16 + t];
    float cwr[5][16];
    #pragma unroll
    for (int k = 0; k < 5; ++k)
        #pragma unroll
        for (int i = 0; i < 16; ++i)
            cwr[k][i] = conv_w[(k * 16 + i) * 64 + t];
    __syncthreads();
    for (int j = t; j < 256; j += 64)
        ch[2 + (j >> 4)][j & 15] = char_embed[(size_t)lab[j >> 4] * 16 + (j & 15)];
    __syncthreads();
    float aw[16];
    const float b = conv_b[t];
    #pragma unroll
    for (int w = 0; w < 16; ++w) aw[w] = b;
    #pragma unroll
    for (int x = 0; x < 20; ++x)
        #pragma unroll
        for (int i = 0; i < 16; ++i) {
            const float chv = ch[x][i];
            #pragma unroll
            for (int k = 0; k < 5; ++k) {
                const int w = x - k;
                if (w >= 0 && w < 16) aw[w] += chv * cwr[k][i];
            }
        }
    float m = 0.f;
    #pragma unroll
    for (int w = 0; w < 16; ++w) m = fmaxf(m, aw[w]);
    lr[(size_t)u * 64 + t] = m;
}

// ---------------------------------------------------------------------------
// h init -> split-tiled (hi+lo bf16). Pads zeroed.
// ---------------------------------------------------------------------------
__global__ void init_h_split(const int* __restrict__ idx, const float* __restrict__ lr,
                             unsigned short* __restrict__ hS, int N, int NP)
{
    const int i = blockIdx.x * blockDim.x + threadIdx.x;
    if (i >= NP * 16) return;
    const int n = i >> 4, kg = i & 15;
    const size_t u = (size_t)(n >> 7) * 32768 + (size_t)kg * 1024 + (size_t)(n & 127) * 8;
    short8 hi, lo;
    if (n < N && kg < 8) {
        const int id = idx[n];
        #pragma unroll
        for (int j = 0; j < 8; ++j) {
            const float v = lr[(size_t)id * 64 + kg * 8 + j];
            float r; hi[j] = (short)bf_hi(v, r); lo[j] = (short)f2bf(r);
        }
    } else {
        #pragma unroll
        for (int j = 0; j < 8; ++j) { hi[j] = 0; lo[j] = 0; }
    }
    *(short8*)(hS + u) = hi;
    *(short8*)(hS + u + 16384) = lo;
}

// ---------------------------------------------------------------------------
// CSR build
// ---------------------------------------------------------------------------
__global__ void hist_kernel(EdgeArgs ea, int* __restrict__ deg, int N)
{
    const int t = blockIdx.y;
    const int e = blockIdx.x * blockDim.x + threadIdx.x;
    if (e >= ea.E[t]) return;
    atomicAdd(&deg[(size_t)t * N + ea.adj[t][2 * e + 1]], 1);
}

__global__ __launch_bounds__(256) void scan_a(const int* __restrict__ deg,
                                              int* __restrict__ partial, int N, int nchunk)
{
    const int t = blockIdx.y, b = blockIdx.x;
    const int base = b * 2048;
    int s = 0;
    for (int i = threadIdx.x; i < 2048; i += 256) {
        const int g = base + i;
        if (g < N) s += deg[(size_t)t * N + g];
    }
    __shared__ int sm[256];
    sm[threadIdx.x] = s; __syncthreads();
    for (int off = 128; off > 0; off >>= 1) {
        if (threadIdx.x < off) sm[threadIdx.x] += sm[threadIdx.x + off];
        __syncthreads();
    }
    if (threadIdx.x == 0) partial[t * nchunk + b] = sm[0];
}

__global__ void scan_b(int* __restrict__ partial, int nchunk)
{
    const int t = threadIdx.x;
    if (t >= 12) return;
    int off = 0;
    for (int i = 0; i < nchunk; ++i) {
        const int s = partial[t * nchunk + i];
        partial[t * nchunk + i] = off;
        off += s;
    }
}

__global__ __launch_bounds__(256) void scan_c(const int* __restrict__ deg,
                                              const int* __restrict__ partial,
                                              int* __restrict__ rowptr, int N, int nchunk)
{
    const int t = blockIdx.y, b = blockIdx.x;
    int* rp = rowptr + (size_t)t * (N + 1);
    const int base = b * 2048;
    int v[8]; int s = 0;
    #pragma unroll
    for (int j = 0; j < 8; ++j) {
        const int g = base + threadIdx.x * 8 + j;
        v[j] = (g < N) ? deg[(size_t)t * N + g] : 0;
        s += v[j];
    }
    __shared__ int ts[256];
    ts[threadIdx.x] = s; __syncthreads();
    for (int off = 1; off < 256; off <<= 1) {
        const int val = (threadIdx.x >= off) ? ts[threadIdx.x - off] : 0;
        __syncthreads();
        ts[threadIdx.x] += val;
        __syncthreads();
    }
    int run = partial[t * nchunk + b] + (threadIdx.x ? ts[threadIdx.x - 1] : 0);
    #pragma unroll
    for (int j = 0; j < 8; ++j) {
        const int g = base + threadIdx.x * 8 + j;
        run += v[j];
        if (g < N) rp[g + 1] = run;
    }
    if (b == 0 && threadIdx.x == 0) rp[0] = 0;
}

__global__ void fill_kernel(EdgeArgs ea, const int* __restrict__ rowptr,
                            int* __restrict__ cursor, int* __restrict__ col, int N)
{
    const int t = blockIdx.y;
    const int e = blockIdx.x * blockDim.x + threadIdx.x;
    if (e >= ea.E[t]) return;
    const int s  = ea.adj[t][2 * e];
    const int tg = ea.adj[t][2 * e + 1];
    const int pos = rowptr[(size_t)t * (N + 1) + tg] + atomicAdd(&cursor[(size_t)t * N + tg], 1);
    col[ea.colOff[t] + pos] = s;
}

// ---------------------------------------------------------------------------
// Weight pre-split into fragment-tiled hi/lo bf16. Matrix m layout:
//   wb[m*32768 + (k>>3)*1024 + c*8 + (k&7)] = hi, +16384 = lo
// m: 0..71 msg (layer*12+t), 72..107 gru (layer*6 + which*3 + slice), 108 w1.
// ---------------------------------------------------------------------------
struct WSrc { const float* wmsg; const float* gk; const float* grk; const float* w1; };

__global__ void split_w_kernel(WSrc s, unsigned short* __restrict__ wb, int nmat)
{
    const int gidx = blockIdx.x * 256 + threadIdx.x;
    const int m = gidx >> 14, e = gidx & 16383;
    if (m >= nmat) return;
    const int kg = e >> 10, rem = e & 1023, c = rem >> 3, j = rem & 7;
    const int k = kg * 8 + j;
    float x;
    if (m < 72) x = s.wmsg[(size_t)m * 16384 + (size_t)k * 128 + c];
    else if (m < 108) {
        const int g = m - 72, layer = g / 6, r2 = g % 6;
        const float* base = (r2 < 3) ? s.gk : s.grk;
        const int slice = r2 % 3;
        x = base[(size_t)layer * 49152 + (size_t)k * 384 + slice * 128 + c];
    } else x = s.w1[(size_t)k * 128 + c];
    float r; const unsigned short hi = bf_hi(x, r);
    wb[(size_t)m * 32768 + e] = hi;
    wb[(size_t)m * 32768 + 16384 + e] = f2bf(r);
}

// ---------------------------------------------------------------------------
// fp32 row-major -> split-tiled hi/lo
// ---------------------------------------------------------------------------
__global__ void split_rows(const float* __restrict__ src, unsigned short* __restrict__ dst, int NP)
{
    const int i = blockIdx.x * blockDim.x + threadIdx.x;
    if (i >= NP * 16) return;
    const int n = i >> 4, kg = i & 15;
    const size_t u = (size_t)(n >> 7) * 32768 + (size_t)kg * 1024 + (size_t)(n & 127) * 8;
    const float4 a = *reinterpret_cast<const float4*>(src + (size_t)n * 128 + kg * 8);
    const float4 b = *reinterpret_cast<const float4*>(src + (size_t)n * 128 + kg * 8 + 4);
    const float v[8] = {a.x, a.y, a.z, a.w, b.x, b.y, b.z, b.w};
    short8 hi, lo;
    #pragma unroll
    for (int j = 0; j < 8; ++j) {
        float r; hi[j] = (short)bf_hi(v[j], r); lo[j] = (short)f2bf(r);
    }
    *(short8*)(dst + u) = hi;
    *(short8*)(dst + u + 16384) = lo;
}

// ---------------------------------------------------------------------------
// MFMA GEMM: C[NP x 128] = act( A1@B1 (+ A2@B2) + bias ), bf16x3 split math.
// A: split-tiled (panel-interleaved) hi/lo. B: 128x128 split matrix.
// No LDS: fragment loads are coalesced straight from L2/L3.
// acts: 0 plain f32, 1 leaky f32, 2 sigmoid f32, 3 sigmoid*h -> split-tiled out.
// outF may alias A1's region (per-block self-overwrite: each block/wave reads
// only its own panel rows before the epilogue writes them).
// ---------------------------------------------------------------------------
struct GemmArgs {
    const unsigned short* A1;
    const unsigned short* A2;   // nullptr -> single pass
    const unsigned short* B1;
    const unsigned short* B2;
    const float*  bias;         // 128 cols or nullptr
    const unsigned short* hRd;  // act 3: h split-tiled
    float*        outF;         // acts 0..2
    unsigned short* outS;       // act 3
    int Mrows;
    int act;
};

__global__ __launch_bounds__(256) void gemm_mfma(GemmArgs ga)
{
    const int blk = blockIdx.x;
    const int tid = threadIdx.x;
    const int lane = tid & 63, w = tid >> 6;
    const int wr = w >> 1, wc = w & 1;
    const int lrow = lane & 15, lkg = lane >> 4;
    const size_t pbase = (size_t)blk * 32768;

    f32x4 acc[4][4] = {};

    for (int pass = 0; pass < 2; ++pass) {
        const unsigned short* Ab = pass ? ga.A2 : ga.A1;
        const unsigned short* Bb = pass ? ga.B2 : ga.B1;
        if (!Ab) break;
        #pragma unroll 1
        for (int c = 0; c < 4; ++c) {
            const int kg = c * 4 + lkg;
            short8 ah[4], al[4], bh[4], bl[4];
            #pragma unroll
            for (int m = 0; m < 4; ++m) {
                const size_t u = pbase + (size_t)kg * 1024 + (size_t)(wr * 64 + m * 16 + lrow) * 8;
                ah[m] = *(const short8*)(Ab + u);
                al[m] = *(const short8*)(Ab + u + 16384);
            }
            #pragma unroll
            for (int n = 0; n < 4; ++n) {
                const size_t u = (size_t)kg * 1024 + (size_t)(wc * 64 + n * 16 + lrow) * 8;
                bh[n] = *(const short8*)(Bb + u);
                bl[n] = *(const short8*)(Bb + u + 16384);
            }
            #pragma unroll
            for (int m = 0; m < 4; ++m)
                #pragma unroll
                for (int n = 0; n < 4; ++n) {
                    acc[m][n] = __builtin_amdgcn_mfma_f32_16x16x32_bf16(ah[m], bh[n], acc[m][n], 0, 0, 0);
                    acc[m][n] = __builtin_amdgcn_mfma_f32_16x16x32_bf16(ah[m], bl[n], acc[m][n], 0, 0, 0);
                    acc[m][n] = __builtin_amdgcn_mfma_f32_16x16x32_bf16(al[m], bh[n], acc[m][n], 0, 0, 0);
                }
        }
    }

    // epilogue: C/D layout col=lane&15, row=(lane>>4)*4+i  [m89-verified]
    #pragma unroll
    for (int m = 0; m < 4; ++m)
        #pragma unroll
        for (int n = 0; n < 4; ++n) {
            const int col = wc * 64 + n * 16 + lrow;
            #pragma unroll
            for (int i = 0; i < 4; ++i) {
                const int rl = wr * 64 + m * 16 + lkg * 4 + i;
                const int r = blk * 128 + rl;
                if (r >= ga.Mrows) continue;
                float v = acc[m][n][i];
                if (ga.bias) v += ga.bias[col];
                if (ga.act == 1) v = v > 0.f ? v : LEAKY_SLOPE * v;
                else if (ga.act >= 2) v = 1.f / (1.f + __expf(-v));
                if (ga.act == 3) {
                    const size_t hu = pbase + (size_t)(col >> 3) * 1024 + (size_t)rl * 8 + (col & 7);
                    const float hv = bf2f(ga.hRd[hu]) + bf2f(ga.hRd[hu + 16384]);
                    const float rh = v * hv;
                    float rem; const unsigned short hi = bf_hi(rh, rem);
                    ga.outS[hu] = hi;
                    ga.outS[hu + 16384] = f2bf(rem);
                } else {
                    ga.outF[(size_t)r * 128 + col] = v;
                }
            }
        }
}

// ---------------------------------------------------------------------------
// CSR gather: agg[n] (+)= sum_{src in in-edges(n)} M[src]. 32 threads/node.
// ---------------------------------------------------------------------------
__global__ __launch_bounds__(256) void gather_csr(
    const int* __restrict__ rowptr, const int* __restrict__ col,
    const float* __restrict__ M, float* __restrict__ agg, int N, int accum)
{
    const int i = blockIdx.x * blockDim.x + threadIdx.x;
    const int n = i >> 5, q = i & 31;
    if (n >= N) return;
    int s = rowptr[n];
    const int e = rowptr[n + 1];
    float4 acc;
    if (accum) acc = *reinterpret_cast<const float4*>(agg + (size_t)n * 128 + (q << 2));
    else       acc = make_float4(0.f, 0.f, 0.f, 0.f);
    for (; s < e; ++s) {
        const int src = col[s];
        const float4 v = *reinterpret_cast<const float4*>(M + (size_t)src * 128 + (q << 2));
        acc.x += v.x; acc.y += v.y; acc.z += v.z; acc.w += v.w;
    }
    *reinterpret_cast<float4*>(agg + (size_t)n * 128 + (q << 2)) = acc;
}

// ---------------------------------------------------------------------------
// GRU final: h = Z*h + (1-Z)*tanh(Gh + G3); h kept split-tiled (in-place).
// ---------------------------------------------------------------------------
__global__ void gru_ew2_split(const float* __restrict__ Z, const float* __restrict__ Gh,
                              const float* __restrict__ G3, unsigned short* __restrict__ hS,
                              int N)
{
    const int i = blockIdx.x * blockDim.x + threadIdx.x;
    if (i >= N * 16) return;
    const int n = i >> 4, kg = i & 15;
    const size_t u = (size_t)(n >> 7) * 32768 + (size_t)kg * 1024 + (size_t)(n & 127) * 8;
    const short8 hi = *(const short8*)(hS + u);
    const short8 lo = *(const short8*)(hS + u + 16384);
    const size_t ro = (size_t)n * 128 + kg * 8;
    short8 nhi, nlo;
    #pragma unroll
    for (int j = 0; j < 8; ++j) {
        const float h = bf2f((unsigned short)hi[j]) + bf2f((unsigned short)lo[j]);
        const float z = Z[ro + j];
        const float hn = z * h + (1.f - z) * tanhf(Gh[ro + j] + G3[ro + j]);
        float r; nhi[j] = (short)bf_hi(hn, r); nlo[j] = (short)f2bf(r);
    }
    *(short8*)(hS + u) = nhi;
    *(short8*)(hS + u + 16384) = nlo;
}

// ---------------------------------------------------------------------------
// Final: thread-per-node; h from split-tiled; wave-uniform graph atomic.
// ---------------------------------------------------------------------------
__global__ __launch_bounds__(256) void final_kernel(
    const unsigned short* __restrict__ hS, const float* __restrict__ V1,
    const int* __restrict__ n2g,
    const float* __restrict__ w2, const float* __restrict__ b2,
    const float* __restrict__ w3, const float* __restrict__ b3,
    const float* __restrict__ w4, const float* __restrict__ b4,
    const float* __restrict__ score_w, const float* __restrict__ score_b,
    float* __restrict__ out, int N)
{
    const int n = blockIdx.x * blockDim.x + threadIdx.x;
    const int nc = n < N ? n : N - 1;
    const int g = n2g[nc];

    float sp = score_b[0];
    #pragma unroll 4
    for (int kg = 0; kg < 16; ++kg) {
        const size_t u = (size_t)(nc >> 7) * 32768 + (size_t)kg * 1024 + (size_t)(nc & 127) * 8;
        const short8 hh = *(const short8*)(hS + u);
        const short8 hl = *(const short8*)(hS + u + 16384);
        #pragma unroll
        for (int j = 0; j < 8; ++j)
            sp += (bf2f((unsigned short)hh[j]) + bf2f((unsigned short)hl[j])) * score_w[kg * 8 + j];
    }

    float V2[32];
    #pragma unroll
    for (int j = 0; j < 32; ++j) V2[j] = b2[j];
    #pragma unroll 2
    for (int k = 0; k < 128; k += 4) {
        const float4 v1 = *reinterpret_cast<const float4*>(V1 + (size_t)nc * 128 + k);
        const float vv[4] = {v1.x, v1.y, v1.z, v1.w};
        #pragma unroll
        for (int kk = 0; kk < 4; ++kk)
            #pragma unroll
            for (int j = 0; j < 32; ++j)
                V2[j] += vv[kk] * w2[(k + kk) * 32 + j];
    }
    #pragma unroll
    for (int j = 0; j < 32; ++j) { const float x = V2[j]; V2[j] = x > 0.f ? x : LEAKY_SLOPE * x; }

    float V3[8];
    #pragma unroll
    for (int j = 0; j < 8; ++j) V3[j] = b3[j];
    #pragma unroll
    for (int k = 0; k < 32; ++k)
        #pragma unroll
        for (int j = 0; j < 8; ++j) V3[j] += V2[k] * w3[k * 8 + j];
    #pragma unroll
    for (int j = 0; j < 8; ++j) { const float x = V3[j]; V3[j] = x > 0.f ? x : LEAKY_SLOPE * x; }

    float o4 = b4[0];
    #pragma unroll
    for (int j = 0; j < 8; ++j) o4 += V3[j] * w4[j];

    const float sc = 1.f / (1.f + __expf(-sp));
    float val = (n < N) ? sc * o4 : 0.f;

    const int g0 = __shfl(g, 0, 64);
    if (__all(g == g0)) {
        #pragma unroll
        for (int d = 32; d > 0; d >>= 1) val += __shfl_xor(val, d, 64);
        if ((threadIdx.x & 63) == 0) unsafeAtomicAdd(out + g0, val);
    } else {
        if (n < N) unsafeAtomicAdd(out + g, val);
    }
}

// ---------------------------------------------------------------------------
extern "C" void kernel_launch(void* const* d_in, const int* in_sizes, int n_in,
                              void* d_out, int out_size, void* d_ws, size_t ws_size,
                              hipStream_t stream)
{
    (void)n_in;
    const int* labels   = (const int*)d_in[1];
    const int* nidx     = (const int*)d_in[2];
    const int* n2g      = (const int*)d_in[3];
    EdgeArgs ea;
    int Emax = 0, Etot = 0;
    for (int t = 0; t < 12; ++t) {
        ea.adj[t] = (const int*)d_in[5 + t];
        ea.E[t] = in_sizes[5 + t] / 2;
        ea.colOff[t] = Etot;
        Etot += ea.E[t];
        if (ea.E[t] > Emax) Emax = ea.E[t];
    }
    const float* char_embed = (const float*)d_in[17];
    const float* conv_w     = (const float*)d_in[18];
    const float* conv_b     = (const float*)d_in[19];
    const float* W_msg      = (const float*)d_in[20];
    const float* gru_k      = (const float*)d_in[21];
    const float* gru_rk     = (const float*)d_in[22];
    const float* gru_b      = (const float*)d_in[23];
    const float* score_w    = (const float*)d_in[24];
    const float* score_b    = (const float*)d_in[25];
    const float* w1 = (const float*)d_in[26];
    const float* b1 = (const float*)d_in[27];
    const float* w2 = (const float*)d_in[28];
    const float* b2 = (const float*)d_in[29];
    const float* w3 = (const float*)d_in[30];
    const float* b3 = (const float*)d_in[31];
    const float* w4 = (const float*)d_in[32];
    const float* b4 = (const float*)d_in[33];

    const int N = in_sizes[2];
    const int U = in_sizes[1] / 16;
    const int G = out_size;
    float* out = (float*)d_out;

    const int NPB = cdiv(N, 128);        // row panels
    const int NP  = NPB * 128;           // padded rows
    const int NCHUNK = cdiv(N, 2048);
    const int NMAT = 109;

    // ---- workspace (float units) ----
    float* ws = (float*)d_ws;
    size_t o = 0;
    float* lr   = ws + o; o += (size_t)U * 64;
    float* hSf  = ws + o; o += (size_t)NP * 128;   // h split-tiled (hi|lo shorts)
    float* Mf   = ws + o; o += (size_t)NP * 128;   // msg out f32 / aggT split / Gh f32
    float* aggf = ws + o; o += (size_t)NP * 128;   // gather accum f32 / Z f32
    float* rhf  = ws + o; o += (size_t)NP * 128;   // rh split / G3 f32
    float* wbf  = ws + o; o += (size_t)NMAT * 16384;
    int* rowptr = (int*)(ws + o);
    int* colarr = rowptr + (size_t)12 * (N + 1);
    const size_t total_bytes = (o + 0) * sizeof(float)
        + ((size_t)12 * (N + 1) + (size_t)Etot) * sizeof(int);
    if (total_bytes > ws_size) return;

    unsigned short* hS  = (unsigned short*)hSf;
    unsigned short* aT  = (unsigned short*)Mf;     // agg split lives in M region
    unsigned short* rhS = (unsigned short*)rhf;
    unsigned short* wb  = (unsigned short*)wbf;

    // CSR temporaries inside M region (free until first msg GEMM)
    int* deg     = (int*)Mf;
    int* cursor  = deg + (size_t)12 * N;
    int* partial = cursor + (size_t)12 * N;

    hipMemsetAsync(d_out, 0, (size_t)G * sizeof(float), stream);
    hipMemsetAsync(deg, 0, ((size_t)24 * N + 12 * NCHUNK) * sizeof(int), stream);

    // ---- CSR build ----
    {
        const dim3 ge(cdiv(Emax, 256), 12);
        const dim3 gs(NCHUNK, 12);
        hist_kernel<<<ge, 256, 0, stream>>>(ea, deg, N);
        scan_a<<<gs, 256, 0, stream>>>(deg, partial, N, NCHUNK);
        scan_b<<<1, 64, 0, stream>>>(partial, NCHUNK);
        scan_c<<<gs, 256, 0, stream>>>(deg, partial, rowptr, N, NCHUNK);
        fill_kernel<<<ge, 256, 0, stream>>>(ea, rowptr, cursor, colarr, N);
    }

    // ---- weight pre-split + h init ----
    WSrc wsrc{W_msg, gru_k, gru_rk, w1};
    split_w_kernel<<<cdiv(NMAT * 16384, 256), 256, 0, stream>>>(wsrc, wb, NMAT);
    label_kernel<<<U, 64, 0, stream>>>(labels, char_embed, conv_w, conv_b, lr, U);
    init_h_split<<<cdiv(NP * 16, 256), 256, 0, stream>>>(nidx, lr, hS, N, NP);

    const int gatherBlocks = cdiv(N * 32, 256);
    const int splitBlocks  = cdiv(NP * 16, 256);
    const int ewBlocks     = cdiv(N * 16, 256);

    for (int layer = 0; layer < 6; ++layer) {
        const float* bl = gru_b + (size_t)layer * 384;
        const int mk  = 72 + layer * 6;       // k slices 0..2, rk slices 3..5
        // message passing
        for (int t = 0; t < 12; ++t) {
            GemmArgs g{};
            g.A1 = hS; g.B1 = wb + (size_t)(layer * 12 + t) * 32768;
            g.outF = Mf; g.Mrows = N; g.act = 0;
            gemm_mfma<<<NPB, 256, 0, stream>>>(g);
            gather_csr<<<gatherBlocks, 256, 0, stream>>>(
                rowptr + (size_t)t * (N + 1), colarr + ea.colOff[t], Mf, aggf, N, t > 0);
        }
        // agg -> split (into M region; msg data fully consumed)
        split_rows<<<splitBlocks, 256, 0, stream>>>(aggf, aT, NP);
        // Z = sigmoid(agg@k0 + h@rk0 + b0) -> agg region (f32)
        {
            GemmArgs g{};
            g.A1 = aT; g.A2 = hS;
            g.B1 = wb + (size_t)(mk + 0) * 32768; g.B2 = wb + (size_t)(mk + 3) * 32768;
            g.bias = bl; g.outF = aggf; g.Mrows = N; g.act = 2;
            gemm_mfma<<<NPB, 256, 0, stream>>>(g);
        }
        // rh = sigmoid(agg@k1 + h@rk1 + b1) * h -> rh split
        {
            GemmArgs g{};
            g.A1 = aT; g.A2 = hS;
            g.B1 = wb + (size_t)(mk + 1) * 32768; g.B2 = wb + (size_t)(mk + 4) * 32768;
            g.bias = bl + 128; g.hRd = hS; g.outS = rhS; g.Mrows = N; g.act = 3;
            gemm_mfma<<<NPB, 256, 0, stream>>>(g);
        }
        // Gh = agg@k2 + b2 -> f32 over aT's own panels (per-block self-overwrite)
        {
            GemmArgs g{};
            g.A1 = aT; g.B1 = wb + (size_t)(mk + 2) * 32768;
            g.bias = bl + 256; g.outF = Mf; g.Mrows = N; g.act = 0;
            gemm_mfma<<<NPB, 256, 0, stream>>>(g);
        }
        // G3 = rh@rk2 -> f32 over rh's own panels
        {
            GemmArgs g{};
            g.A1 = rhS; g.B1 = wb + (size_t)(mk + 5) * 32768;
            g.outF = rhf; g.Mrows = N; g.act = 0;
            gemm_mfma<<<NPB, 256, 0, stream>>>(g);
        }
        // h = Z*h + (1-Z)*tanh(Gh + G3)
        gru_ew2_split<<<ewBlocks, 256, 0, stream>>>(aggf, Mf, rhf, hS, N);
    }
    // V1 = leaky(h @ w1 + b1) -> M (f32)
    {
        GemmArgs g{};
        g.A1 = hS; g.B1 = wb + (size_t)108 * 32768;
        g.bias = b1; g.outF = Mf; g.Mrows = N; g.act = 1;
        gemm_mfma<<<NPB, 256, 0, stream>>>(g);
    }
    final_kernel<<<cdiv(N, 256), 256, 0, stream>>>(hS, Mf, n2g, w2, b2, w3, b3, w4, b4,
                                                   score_w, score_b, out, N);
}

// Round 5
// 4307.159 us; speedup vs baseline: 4.3639x; 1.3870x over previous
//
#include <hip/hip_runtime.h>
#include <hip/hip_bf16.h>

#define LEAKY_SLOPE 0.2f

typedef short short8 __attribute__((ext_vector_type(8)));
typedef short short4v __attribute__((ext_vector_type(4)));
typedef float f32x4 __attribute__((ext_vector_type(4)));

static inline int cdiv(int a, int b) { return (a + b - 1) / b; }

// ---- bf16 split helpers (RNE) ----------------------------------------------
__device__ __forceinline__ float bf2f(unsigned short s) {
    return __uint_as_float(((unsigned int)s) << 16);
}
__device__ __forceinline__ unsigned short f2bf(float x) {
    unsigned int u = __float_as_uint(x);
    return (unsigned short)((u + 0x7FFFu + ((u >> 16) & 1u)) >> 16);
}
__device__ __forceinline__ unsigned short bf_hi(float x, float& rem) {
    unsigned int u = __float_as_uint(x);
    unsigned int hi = (u + 0x7FFFu + ((u >> 16) & 1u)) & 0xFFFF0000u;
    rem = x - __uint_as_float(hi);
    return (unsigned short)(hi >> 16);
}
// split-tiled layout: elem (row r, feat k) of an NPx128 matrix lives at unit
//   panel(r>>7)*32768 + (k>>3)*1024 + (r&127)*8 + (k&7);  lo plane at +16384.

struct EdgeArgs {
    const int* adj[12];
    int E[12];
    int colOff[12];
};

// ---------------------------------------------------------------------------
// Label representation: char-CNN + relu + max over positions.
// ---------------------------------------------------------------------------
__global__ __launch_bounds__(64) void label_kernel(
    const int* __restrict__ labels, const float* __restrict__ char_embed,
    const float* __restrict__ conv_w, const float* __restrict__ conv_b,
    float* __restrict__ lr, int U)
{
    __shared__ float ch[20][16];
    __shared__ int lab[16];
    const int u = blockIdx.x, t = threadIdx.x;
    {
        const int r = t >> 4, i = t & 15;
        const int padrow[4] = {0, 1, 18, 19};
        ch[padrow[r]][i] = 0.f;
    }
    if (t < 16) lab[t] = labels[(size_t)u * 16 + t];
    float cwr[5][16];
    #pragma unroll
    for (int k = 0; k < 5; ++k)
        #pragma unroll
        for (int i = 0; i < 16; ++i)
            cwr[k][i] = conv_w[(k * 16 + i) * 64 + t];
    __syncthreads();
    for (int j = t; j < 256; j += 64)
        ch[2 + (j >> 4)][j & 15] = char_embed[(size_t)lab[j >> 4] * 16 + (j & 15)];
    __syncthreads();
    float aw[16];
    const float b = conv_b[t];
    #pragma unroll
    for (int w = 0; w < 16; ++w) aw[w] = b;
    #pragma unroll
    for (int x = 0; x < 20; ++x)
        #pragma unroll
        for (int i = 0; i < 16; ++i) {
            const float chv = ch[x][i];
            #pragma unroll
            for (int k = 0; k < 5; ++k) {
                const int w = x - k;
                if (w >= 0 && w < 16) aw[w] += chv * cwr[k][i];
            }
        }
    float m = 0.f;
    #pragma unroll
    for (int w = 0; w < 16; ++w) m = fmaxf(m, aw[w]);
    lr[(size_t)u * 64 + t] = m;
}

// ---------------------------------------------------------------------------
// h init -> split-tiled (hi+lo bf16). Pads zeroed.
// ---------------------------------------------------------------------------
__global__ void init_h_split(const int* __restrict__ idx, const float* __restrict__ lr,
                             unsigned short* __restrict__ hS, int N, int NP)
{
    const int i = blockIdx.x * blockDim.x + threadIdx.x;
    if (i >= NP * 16) return;
    const int n = i >> 4, kg = i & 15;
    const size_t u = (size_t)(n >> 7) * 32768 + (size_t)kg * 1024 + (size_t)(n & 127) * 8;
    short8 hi, lo;
    if (n < N && kg < 8) {
        const int id = idx[n];
        #pragma unroll
        for (int j = 0; j < 8; ++j) {
            const float v = lr[(size_t)id * 64 + kg * 8 + j];
            float r; hi[j] = (short)bf_hi(v, r); lo[j] = (short)f2bf(r);
        }
    } else {
        #pragma unroll
        for (int j = 0; j < 8; ++j) { hi[j] = 0; lo[j] = 0; }
    }
    *(short8*)(hS + u) = hi;
    *(short8*)(hS + u + 16384) = lo;
}

// ---------------------------------------------------------------------------
// CSR build
// ---------------------------------------------------------------------------
__global__ void hist_kernel(EdgeArgs ea, int* __restrict__ deg, int N)
{
    const int t = blockIdx.y;
    const int e = blockIdx.x * blockDim.x + threadIdx.x;
    if (e >= ea.E[t]) return;
    atomicAdd(&deg[(size_t)t * N + ea.adj[t][2 * e + 1]], 1);
}

__global__ __launch_bounds__(256) void scan_a(const int* __restrict__ deg,
                                              int* __restrict__ partial, int N, int nchunk)
{
    const int t = blockIdx.y, b = blockIdx.x;
    const int base = b * 2048;
    int s = 0;
    for (int i = threadIdx.x; i < 2048; i += 256) {
        const int g = base + i;
        if (g < N) s += deg[(size_t)t * N + g];
    }
    __shared__ int sm[256];
    sm[threadIdx.x] = s; __syncthreads();
    for (int off = 128; off > 0; off >>= 1) {
        if (threadIdx.x < off) sm[threadIdx.x] += sm[threadIdx.x + off];
        __syncthreads();
    }
    if (threadIdx.x == 0) partial[t * nchunk + b] = sm[0];
}

__global__ void scan_b(int* __restrict__ partial, int nchunk)
{
    const int t = threadIdx.x;
    if (t >= 12) return;
    int off = 0;
    for (int i = 0; i < nchunk; ++i) {
        const int s = partial[t * nchunk + i];
        partial[t * nchunk + i] = off;
        off += s;
    }
}

__global__ __launch_bounds__(256) void scan_c(const int* __restrict__ deg,
                                              const int* __restrict__ partial,
                                              int* __restrict__ rowptr, int N, int nchunk)
{
    const int t = blockIdx.y, b = blockIdx.x;
    int* rp = rowptr + (size_t)t * (N + 1);
    const int base = b * 2048;
    int v[8]; int s = 0;
    #pragma unroll
    for (int j = 0; j < 8; ++j) {
        const int g = base + threadIdx.x * 8 + j;
        v[j] = (g < N) ? deg[(size_t)t * N + g] : 0;
        s += v[j];
    }
    __shared__ int ts[256];
    ts[threadIdx.x] = s; __syncthreads();
    for (int off = 1; off < 256; off <<= 1) {
        const int val = (threadIdx.x >= off) ? ts[threadIdx.x - off] : 0;
        __syncthreads();
        ts[threadIdx.x] += val;
        __syncthreads();
    }
    int run = partial[t * nchunk + b] + (threadIdx.x ? ts[threadIdx.x - 1] : 0);
    #pragma unroll
    for (int j = 0; j < 8; ++j) {
        const int g = base + threadIdx.x * 8 + j;
        run += v[j];
        if (g < N) rp[g + 1] = run;
    }
    if (b == 0 && threadIdx.x == 0) rp[0] = 0;
}

__global__ void fill_kernel(EdgeArgs ea, const int* __restrict__ rowptr,
                            int* __restrict__ cursor, int* __restrict__ col, int N)
{
    const int t = blockIdx.y;
    const int e = blockIdx.x * blockDim.x + threadIdx.x;
    if (e >= ea.E[t]) return;
    const int s  = ea.adj[t][2 * e];
    const int tg = ea.adj[t][2 * e + 1];
    const int pos = rowptr[(size_t)t * (N + 1) + tg] + atomicAdd(&cursor[(size_t)t * N + tg], 1);
    col[ea.colOff[t] + pos] = s;
}

// ---------------------------------------------------------------------------
// Weight pre-split into fragment-tiled hi/lo bf16 (unchanged from r4).
// ---------------------------------------------------------------------------
struct WSrc { const float* wmsg; const float* gk; const float* grk; const float* w1; };

__global__ void split_w_kernel(WSrc s, unsigned short* __restrict__ wb, int nmat)
{
    const int gidx = blockIdx.x * 256 + threadIdx.x;
    const int m = gidx >> 14, e = gidx & 16383;
    if (m >= nmat) return;
    const int kg = e >> 10, rem = e & 1023, c = rem >> 3, j = rem & 7;
    const int k = kg * 8 + j;
    float x;
    if (m < 72) x = s.wmsg[(size_t)m * 16384 + (size_t)k * 128 + c];
    else if (m < 108) {
        const int g = m - 72, layer = g / 6, r2 = g % 6;
        const float* base = (r2 < 3) ? s.gk : s.grk;
        const int slice = r2 % 3;
        x = base[(size_t)layer * 49152 + (size_t)k * 384 + slice * 128 + c];
    } else x = s.w1[(size_t)k * 128 + c];
    float r; const unsigned short hi = bf_hi(x, r);
    wb[(size_t)m * 32768 + e] = hi;
    wb[(size_t)m * 32768 + 16384 + e] = f2bf(r);
}

// ---------------------------------------------------------------------------
// LDS staging of one 64KB split panel (reg-staged: coalesced 16B loads +
// ds_write_b128). Caller must __syncthreads() after.
// ---------------------------------------------------------------------------
__device__ __forceinline__ void stage_panel(const unsigned short* __restrict__ g,
                                            unsigned short* __restrict__ lds, int tid)
{
    #pragma unroll
    for (int i = 0; i < 16; ++i) {
        const int uo = i * 2048 + tid * 8;
        *(short8*)(lds + uo) = *(const short8*)(g + uo);
    }
}

// ---------------------------------------------------------------------------
// One full K=128 MFMA sweep: A from LDS, NM B-matrices from global (L2-hot).
// acc[t] += A @ B[t]  (bf16x3 split: hh + hl + lh)
// ---------------------------------------------------------------------------
template<int NM>
__device__ __forceinline__ void mfma_pass(const unsigned short* __restrict__ lds,
                                          const unsigned short* const* Bs,
                                          f32x4 (&acc)[NM][4][4],
                                          int wr, int wc, int lrow, int lkg)
{
    #pragma unroll 1
    for (int c = 0; c < 4; ++c) {
        const int kg = c * 4 + lkg;
        short8 ah[4], al[4];
        #pragma unroll
        for (int m = 0; m < 4; ++m) {
            const int u = kg * 1024 + (wr * 64 + m * 16 + lrow) * 8;
            ah[m] = *(const short8*)(lds + u);
            al[m] = *(const short8*)(lds + u + 16384);
        }
        #pragma unroll
        for (int t = 0; t < NM; ++t) {
            const unsigned short* __restrict__ B = Bs[t];
            short8 bh[4], bl[4];
            #pragma unroll
            for (int n = 0; n < 4; ++n) {
                const int u = kg * 1024 + (wc * 64 + n * 16 + lrow) * 8;
                bh[n] = *(const short8*)(B + u);
                bl[n] = *(const short8*)(B + u + 16384);
            }
            #pragma unroll
            for (int m = 0; m < 4; ++m)
                #pragma unroll
                for (int n = 0; n < 4; ++n) {
                    acc[t][m][n] = __builtin_amdgcn_mfma_f32_16x16x32_bf16(ah[m], bh[n], acc[t][m][n], 0, 0, 0);
                    acc[t][m][n] = __builtin_amdgcn_mfma_f32_16x16x32_bf16(ah[m], bl[n], acc[t][m][n], 0, 0, 0);
                    acc[t][m][n] = __builtin_amdgcn_mfma_f32_16x16x32_bf16(al[m], bh[n], acc[t][m][n], 0, 0, 0);
                }
        }
    }
}

// ---------------------------------------------------------------------------
// Message GEMM: stage h panel once; compute NM outputs (NM B-matrices).
// ---------------------------------------------------------------------------
template<int NM>
__global__ __launch_bounds__(256) void msg_kernel(
    const unsigned short* __restrict__ hS,
    const unsigned short* __restrict__ B0, const unsigned short* __restrict__ B1,
    float* __restrict__ out0, float* __restrict__ out1)
{
    __shared__ unsigned short lds[32768];
    const int tid = threadIdx.x;
    stage_panel(hS + (size_t)blockIdx.x * 32768, lds, tid);
    const int wave = tid >> 6, lane = tid & 63;
    const int wr = wave >> 1, wc = wave & 1, lrow = lane & 15, lkg = lane >> 4;
    f32x4 acc[NM][4][4] = {};
    __syncthreads();
    const unsigned short* Bs[2] = {B0, B1};
    mfma_pass<NM>(lds, Bs, acc, wr, wc, lrow, lkg);
    const size_t rowBase = (size_t)blockIdx.x * 128;
    #pragma unroll
    for (int t = 0; t < NM; ++t) {
        float* __restrict__ op = t ? out1 : out0;
        #pragma unroll
        for (int m = 0; m < 4; ++m)
            #pragma unroll
            for (int n = 0; n < 4; ++n) {
                const int col = wc * 64 + n * 16 + lrow;
                #pragma unroll
                for (int i = 0; i < 4; ++i) {
                    const size_t r = rowBase + wr * 64 + m * 16 + lkg * 4 + i;
                    op[r * 128 + col] = acc[t][m][n][i];
                }
            }
    }
}

// ---------------------------------------------------------------------------
// Fused Z+R GEMM: acc0 = agg@k0 + h@rk0, acc1 = agg@k1 + h@rk1 (two stages).
// Epilogue: Z = sigmoid(acc0+bz) -> f32;  rh = sigmoid(acc1+br)*h -> split.
// h read from LDS (still holds the hS panel from pass 2).
// ---------------------------------------------------------------------------
__global__ __launch_bounds__(256) void zr_kernel(
    const unsigned short* __restrict__ aT, const unsigned short* __restrict__ hS,
    const unsigned short* __restrict__ k0, const unsigned short* __restrict__ k1,
    const unsigned short* __restrict__ rk0, const unsigned short* __restrict__ rk1,
    const float* __restrict__ bias,              // 256: z|r
    float* __restrict__ zOut, unsigned short* __restrict__ rhS)
{
    __shared__ unsigned short lds[32768];
    const int tid = threadIdx.x;
    const size_t pbase = (size_t)blockIdx.x * 32768;
    const int wave = tid >> 6, lane = tid & 63;
    const int wr = wave >> 1, wc = wave & 1, lrow = lane & 15, lkg = lane >> 4;
    f32x4 acc[2][4][4] = {};

    stage_panel(aT + pbase, lds, tid);
    __syncthreads();
    { const unsigned short* Bs[2] = {k0, k1};  mfma_pass<2>(lds, Bs, acc, wr, wc, lrow, lkg); }
    __syncthreads();
    stage_panel(hS + pbase, lds, tid);
    __syncthreads();
    { const unsigned short* Bs[2] = {rk0, rk1}; mfma_pass<2>(lds, Bs, acc, wr, wc, lrow, lkg); }

    const size_t rowBase = (size_t)blockIdx.x * 128;
    #pragma unroll
    for (int m = 0; m < 4; ++m)
        #pragma unroll
        for (int n = 0; n < 4; ++n) {
            const int col = wc * 64 + n * 16 + lrow;
            #pragma unroll
            for (int i = 0; i < 4; ++i) {
                const int rl = wr * 64 + m * 16 + lkg * 4 + i;
                const float z = 1.f / (1.f + __expf(-(acc[0][m][n][i] + bias[col])));
                zOut[(rowBase + rl) * 128 + col] = z;
                const float v = 1.f / (1.f + __expf(-(acc[1][m][n][i] + bias[128 + col])));
                const int hu = (col >> 3) * 1024 + rl * 8 + (col & 7);
                const float hval = bf2f(lds[hu]) + bf2f(lds[hu + 16384]);
                const float rh = v * hval;
                float rem; const unsigned short hi = bf_hi(rh, rem);
                rhS[pbase + hu] = hi;
                rhS[pbase + hu + 16384] = f2bf(rem);
            }
        }
}

// ---------------------------------------------------------------------------
// General staged GEMM (1 or 2 A@B terms summed), f32 out, act 0=none 1=leaky.
// Used for G = agg@k2 + rh@rk2 + b (fused Gh+G3) and V1 = leaky(h@w1+b1).
// outF may alias A1/A2 region (per-block self-overwrite after staging).
// ---------------------------------------------------------------------------
__global__ __launch_bounds__(256) void gemm_lds(
    const unsigned short* __restrict__ A1, const unsigned short* __restrict__ B1,
    const unsigned short* __restrict__ A2, const unsigned short* __restrict__ B2,
    const float* __restrict__ bias, float* __restrict__ outF, int act)
{
    __shared__ unsigned short lds[32768];
    const int tid = threadIdx.x;
    const size_t pbase = (size_t)blockIdx.x * 32768;
    const int wave = tid >> 6, lane = tid & 63;
    const int wr = wave >> 1, wc = wave & 1, lrow = lane & 15, lkg = lane >> 4;
    f32x4 acc[1][4][4] = {};

    stage_panel(A1 + pbase, lds, tid);
    __syncthreads();
    { const unsigned short* Bs[2] = {B1, nullptr}; mfma_pass<1>(lds, Bs, acc, wr, wc, lrow, lkg); }
    if (A2) {
        __syncthreads();
        stage_panel(A2 + pbase, lds, tid);
        __syncthreads();
        const unsigned short* Bs[2] = {B2, nullptr};
        mfma_pass<1>(lds, Bs, acc, wr, wc, lrow, lkg);
    }
    const size_t rowBase = (size_t)blockIdx.x * 128;
    #pragma unroll
    for (int m = 0; m < 4; ++m)
        #pragma unroll
        for (int n = 0; n < 4; ++n) {
            const int col = wc * 64 + n * 16 + lrow;
            #pragma unroll
            for (int i = 0; i < 4; ++i) {
                const int rl = wr * 64 + m * 16 + lkg * 4 + i;
                float v = acc[0][m][n][i];
                if (bias) v += bias[col];
                if (act == 1) v = v > 0.f ? v : LEAKY_SLOPE * v;
                outF[(rowBase + rl) * 128 + col] = v;
            }
        }
}

// ---------------------------------------------------------------------------
// Gathers. 32 threads/node, float4 rows.
// ---------------------------------------------------------------------------
__global__ __launch_bounds__(256) void gather_csr(
    const int* __restrict__ rowptr, const int* __restrict__ col,
    const float* __restrict__ M, float* __restrict__ agg, int N, int accum)
{
    const int i = blockIdx.x * blockDim.x + threadIdx.x;
    const int n = i >> 5, q = i & 31;
    if (n >= N) return;
    float4 acc;
    if (accum) acc = *reinterpret_cast<const float4*>(agg + (size_t)n * 128 + (q << 2));
    else       acc = make_float4(0.f, 0.f, 0.f, 0.f);
    for (int s = rowptr[n]; s < rowptr[n + 1]; ++s) {
        const float4 v = *reinterpret_cast<const float4*>(M + (size_t)col[s] * 128 + (q << 2));
        acc.x += v.x; acc.y += v.y; acc.z += v.z; acc.w += v.w;
    }
    *reinterpret_cast<float4*>(agg + (size_t)n * 128 + (q << 2)) = acc;
}

__global__ __launch_bounds__(256) void gather2_csr(
    const int* __restrict__ rp0, const int* __restrict__ c0, const float* __restrict__ M0,
    const int* __restrict__ rp1, const int* __restrict__ c1, const float* __restrict__ M1,
    float* __restrict__ agg, int N, int accum)
{
    const int i = blockIdx.x * blockDim.x + threadIdx.x;
    const int n = i >> 5, q = i & 31;
    if (n >= N) return;
    float4 acc;
    if (accum) acc = *reinterpret_cast<const float4*>(agg + (size_t)n * 128 + (q << 2));
    else       acc = make_float4(0.f, 0.f, 0.f, 0.f);
    for (int s = rp0[n]; s < rp0[n + 1]; ++s) {
        const float4 v = *reinterpret_cast<const float4*>(M0 + (size_t)c0[s] * 128 + (q << 2));
        acc.x += v.x; acc.y += v.y; acc.z += v.z; acc.w += v.w;
    }
    for (int s = rp1[n]; s < rp1[n + 1]; ++s) {
        const float4 v = *reinterpret_cast<const float4*>(M1 + (size_t)c1[s] * 128 + (q << 2));
        acc.x += v.x; acc.y += v.y; acc.z += v.z; acc.w += v.w;
    }
    *reinterpret_cast<float4*>(agg + (size_t)n * 128 + (q << 2)) = acc;
}

// Final gather of the layer: add last etype, emit agg directly split-tiled.
__global__ __launch_bounds__(256) void gather_split_csr(
    const int* __restrict__ rp, const int* __restrict__ cl, const float* __restrict__ M,
    const float* __restrict__ agg, unsigned short* __restrict__ aT, int N, int NP)
{
    const int i = blockIdx.x * blockDim.x + threadIdx.x;
    const int n = i >> 5, q = i & 31;
    if (n >= NP) return;
    float4 a = make_float4(0.f, 0.f, 0.f, 0.f);
    if (n < N) {
        a = *reinterpret_cast<const float4*>(agg + (size_t)n * 128 + (q << 2));
        for (int s = rp[n]; s < rp[n + 1]; ++s) {
            const float4 v = *reinterpret_cast<const float4*>(M + (size_t)cl[s] * 128 + (q << 2));
            a.x += v.x; a.y += v.y; a.z += v.z; a.w += v.w;
        }
    }
    const size_t u = (size_t)(n >> 7) * 32768 + (size_t)(q >> 1) * 1024
                   + (size_t)(n & 127) * 8 + (q & 1) * 4;
    const float vv[4] = {a.x, a.y, a.z, a.w};
    short4v hi, lo;
    #pragma unroll
    for (int j = 0; j < 4; ++j) {
        float r; hi[j] = (short)bf_hi(vv[j], r); lo[j] = (short)f2bf(r);
    }
    *(short4v*)(aT + u) = hi;
    *(short4v*)(aT + u + 16384) = lo;
}

// ---------------------------------------------------------------------------
// GRU final: h = Z*h + (1-Z)*tanh(G); h kept split-tiled (in-place).
// ---------------------------------------------------------------------------
__global__ void gru_ew2_split(const float* __restrict__ Z, const float* __restrict__ G,
                              unsigned short* __restrict__ hS, int N)
{
    const int i = blockIdx.x * blockDim.x + threadIdx.x;
    if (i >= N * 16) return;
    const int n = i >> 4, kg = i & 15;
    const size_t u = (size_t)(n >> 7) * 32768 + (size_t)kg * 1024 + (size_t)(n & 127) * 8;
    const short8 hi = *(const short8*)(hS + u);
    const short8 lo = *(const short8*)(hS + u + 16384);
    const size_t ro = (size_t)n * 128 + kg * 8;
    short8 nhi, nlo;
    #pragma unroll
    for (int j = 0; j < 8; ++j) {
        const float h = bf2f((unsigned short)hi[j]) + bf2f((unsigned short)lo[j]);
        const float z = Z[ro + j];
        const float hn = z * h + (1.f - z) * tanhf(G[ro + j]);
        float r; nhi[j] = (short)bf_hi(hn, r); nlo[j] = (short)f2bf(r);
    }
    *(short8*)(hS + u) = nhi;
    *(short8*)(hS + u + 16384) = nlo;
}

// ---------------------------------------------------------------------------
// Final: thread-per-node; wave-uniform graph atomic (n2g sorted).
// ---------------------------------------------------------------------------
__global__ __launch_bounds__(256) void final_kernel(
    const unsigned short* __restrict__ hS, const float* __restrict__ V1,
    const int* __restrict__ n2g,
    const float* __restrict__ w2, const float* __restrict__ b2,
    const float* __restrict__ w3, const float* __restrict__ b3,
    const float* __restrict__ w4, const float* __restrict__ b4,
    const float* __restrict__ score_w, const float* __restrict__ score_b,
    float* __restrict__ out, int N)
{
    const int n = blockIdx.x * blockDim.x + threadIdx.x;
    const int nc = n < N ? n : N - 1;
    const int g = n2g[nc];

    float sp = score_b[0];
    #pragma unroll 4
    for (int kg = 0; kg < 16; ++kg) {
        const size_t u = (size_t)(nc >> 7) * 32768 + (size_t)kg * 1024 + (size_t)(nc & 127) * 8;
        const short8 hh = *(const short8*)(hS + u);
        const short8 hl = *(const short8*)(hS + u + 16384);
        #pragma unroll
        for (int j = 0; j < 8; ++j)
            sp += (bf2f((unsigned short)hh[j]) + bf2f((unsigned short)hl[j])) * score_w[kg * 8 + j];
    }

    float V2[32];
    #pragma unroll
    for (int j = 0; j < 32; ++j) V2[j] = b2[j];
    #pragma unroll 2
    for (int k = 0; k < 128; k += 4) {
        const float4 v1 = *reinterpret_cast<const float4*>(V1 + (size_t)nc * 128 + k);
        const float vv[4] = {v1.x, v1.y, v1.z, v1.w};
        #pragma unroll
        for (int kk = 0; kk < 4; ++kk)
            #pragma unroll
            for (int j = 0; j < 32; ++j)
                V2[j] += vv[kk] * w2[(k + kk) * 32 + j];
    }
    #pragma unroll
    for (int j = 0; j < 32; ++j) { const float x = V2[j]; V2[j] = x > 0.f ? x : LEAKY_SLOPE * x; }

    float V3[8];
    #pragma unroll
    for (int j = 0; j < 8; ++j) V3[j] = b3[j];
    #pragma unroll
    for (int k = 0; k < 32; ++k)
        #pragma unroll
        for (int j = 0; j < 8; ++j) V3[j] += V2[k] * w3[k * 8 + j];
    #pragma unroll
    for (int j = 0; j < 8; ++j) { const float x = V3[j]; V3[j] = x > 0.f ? x : LEAKY_SLOPE * x; }

    float o4 = b4[0];
    #pragma unroll
    for (int j = 0; j < 8; ++j) o4 += V3[j] * w4[j];

    const float sc = 1.f / (1.f + __expf(-sp));
    float val = (n < N) ? sc * o4 : 0.f;

    const int g0 = __shfl(g, 0, 64);
    if (__all(g == g0)) {
        #pragma unroll
        for (int d = 32; d > 0; d >>= 1) val += __shfl_xor(val, d, 64);
        if ((threadIdx.x & 63) == 0) unsafeAtomicAdd(out + g0, val);
    } else {
        if (n < N) unsafeAtomicAdd(out + g, val);
    }
}

// ---------------------------------------------------------------------------
extern "C" void kernel_launch(void* const* d_in, const int* in_sizes, int n_in,
                              void* d_out, int out_size, void* d_ws, size_t ws_size,
                              hipStream_t stream)
{
    (void)n_in;
    const int* labels   = (const int*)d_in[1];
    const int* nidx     = (const int*)d_in[2];
    const int* n2g      = (const int*)d_in[3];
    EdgeArgs ea;
    int Emax = 0, Etot = 0;
    for (int t = 0; t < 12; ++t) {
        ea.adj[t] = (const int*)d_in[5 + t];
        ea.E[t] = in_sizes[5 + t] / 2;
        ea.colOff[t] = Etot;
        Etot += ea.E[t];
        if (ea.E[t] > Emax) Emax = ea.E[t];
    }
    const float* char_embed = (const float*)d_in[17];
    const float* conv_w     = (const float*)d_in[18];
    const float* conv_b     = (const float*)d_in[19];
    const float* W_msg      = (const float*)d_in[20];
    const float* gru_k      = (const float*)d_in[21];
    const float* gru_rk     = (const float*)d_in[22];
    const float* gru_b      = (const float*)d_in[23];
    const float* score_w    = (const float*)d_in[24];
    const float* score_b    = (const float*)d_in[25];
    const float* w1 = (const float*)d_in[26];
    const float* b1 = (const float*)d_in[27];
    const float* w2 = (const float*)d_in[28];
    const float* b2 = (const float*)d_in[29];
    const float* w3 = (const float*)d_in[30];
    const float* b3 = (const float*)d_in[31];
    const float* w4 = (const float*)d_in[32];
    const float* b4 = (const float*)d_in[33];

    const int N = in_sizes[2];
    const int U = in_sizes[1] / 16;
    const int G = out_size;
    float* out = (float*)d_out;

    const int NPB = cdiv(N, 128);
    const int NP  = NPB * 128;
    const int NCHUNK = cdiv(N, 2048);
    const int NMAT = 109;

    // ---- workspace ----
    float* ws = (float*)d_ws;
    size_t o = 0;
    float* lr   = ws + o; o += (size_t)U * 64;
    float* hSf  = ws + o; o += (size_t)NP * 128;   // h split-tiled
    float* Mf   = ws + o; o += (size_t)NP * 128;   // M0 f32 / aT split / G f32
    float* aggf = ws + o; o += (size_t)NP * 128;   // agg f32 -> Z f32
    float* rhf  = ws + o; o += (size_t)NP * 128;   // M1 f32 / rh split
    float* wbf  = ws + o; o += (size_t)NMAT * 16384;
    int* rowptr = (int*)(ws + o);
    int* colarr = rowptr + (size_t)12 * (N + 1);
    const size_t total_bytes = o * sizeof(float)
        + ((size_t)12 * (N + 1) + (size_t)Etot) * sizeof(int);
    if (total_bytes > ws_size) return;

    unsigned short* hS  = (unsigned short*)hSf;
    unsigned short* aT  = (unsigned short*)Mf;
    unsigned short* rhS = (unsigned short*)rhf;
    unsigned short* wb  = (unsigned short*)wbf;

    // CSR temporaries inside M region (free until first msg GEMM)
    int* deg     = (int*)Mf;
    int* cursor  = deg + (size_t)12 * N;
    int* partial = cursor + (size_t)12 * N;

    hipMemsetAsync(d_out, 0, (size_t)G * sizeof(float), stream);
    hipMemsetAsync(deg, 0, ((size_t)24 * N + 12 * NCHUNK) * sizeof(int), stream);

    {
        const dim3 ge(cdiv(Emax, 256), 12);
        const dim3 gs(NCHUNK, 12);
        hist_kernel<<<ge, 256, 0, stream>>>(ea, deg, N);
        scan_a<<<gs, 256, 0, stream>>>(deg, partial, N, NCHUNK);
        scan_b<<<1, 64, 0, stream>>>(partial, NCHUNK);
        scan_c<<<gs, 256, 0, stream>>>(deg, partial, rowptr, N, NCHUNK);
        fill_kernel<<<ge, 256, 0, stream>>>(ea, rowptr, cursor, colarr, N);
    }

    WSrc wsrc{W_msg, gru_k, gru_rk, w1};
    split_w_kernel<<<cdiv(NMAT * 16384, 256), 256, 0, stream>>>(wsrc, wb, NMAT);
    label_kernel<<<U, 64, 0, stream>>>(labels, char_embed, conv_w, conv_b, lr, U);
    init_h_split<<<cdiv(NP * 16, 256), 256, 0, stream>>>(nidx, lr, hS, N, NP);

    const int gatherBlocks = cdiv(N * 32, 256);
    const int gatherBlocksNP = cdiv(NP * 32, 256);
    const int ewBlocks = cdiv(N * 16, 256);
    auto rp  = [&](int t) { return rowptr + (size_t)t * (N + 1); };
    auto cp  = [&](int t) { return colarr + ea.colOff[t]; };
    auto wbm = [&](int m) { return wb + (size_t)m * 32768; };

    for (int layer = 0; layer < 6; ++layer) {
        const float* bl = gru_b + (size_t)layer * 384;
        const int mk = 72 + layer * 6;
        // message passing: 5 fused pairs + 2 singles (last emits split agg)
        for (int p = 0; p < 5; ++p) {
            const int t0 = 2 * p, t1 = 2 * p + 1;
            msg_kernel<2><<<NPB, 256, 0, stream>>>(hS, wbm(layer * 12 + t0), wbm(layer * 12 + t1), Mf, rhf);
            gather2_csr<<<gatherBlocks, 256, 0, stream>>>(rp(t0), cp(t0), Mf,
                                                          rp(t1), cp(t1), rhf, aggf, N, p > 0);
        }
        msg_kernel<1><<<NPB, 256, 0, stream>>>(hS, wbm(layer * 12 + 10), nullptr, Mf, nullptr);
        gather_csr<<<gatherBlocks, 256, 0, stream>>>(rp(10), cp(10), Mf, aggf, N, 1);
        msg_kernel<1><<<NPB, 256, 0, stream>>>(hS, wbm(layer * 12 + 11), nullptr, rhf, nullptr);
        gather_split_csr<<<gatherBlocksNP, 256, 0, stream>>>(rp(11), cp(11), rhf, aggf, aT, N, NP);
        // Z + rh (fused, dual-stage)
        zr_kernel<<<NPB, 256, 0, stream>>>(aT, hS, wbm(mk + 0), wbm(mk + 1),
                                           wbm(mk + 3), wbm(mk + 4), bl, aggf, rhS);
        // G = agg@k2 + rh@rk2 + b  (fused Gh+G3)
        gemm_lds<<<NPB, 256, 0, stream>>>(aT, wbm(mk + 2), rhS, wbm(mk + 5), bl + 256, Mf, 0);
        // h = Z*h + (1-Z)*tanh(G)
        gru_ew2_split<<<ewBlocks, 256, 0, stream>>>(aggf, Mf, hS, N);
    }
    // V1 = leaky(h @ w1 + b1)
    gemm_lds<<<NPB, 256, 0, stream>>>(hS, wbm(108), nullptr, nullptr, b1, Mf, 1);
    final_kernel<<<cdiv(N, 256), 256, 0, stream>>>(hS, Mf, n2g, w2, b2, w3, b3, w4, b4,
                                                   score_w, score_b, out, N);
}

// Round 6
// 4255.655 us; speedup vs baseline: 4.4167x; 1.0121x over previous
//
#include <hip/hip_runtime.h>
#include <hip/hip_bf16.h>

#define LEAKY_SLOPE 0.2f

typedef short short8 __attribute__((ext_vector_type(8)));
typedef short short4v __attribute__((ext_vector_type(4)));
typedef float f32x4 __attribute__((ext_vector_type(4)));

static inline int cdiv(int a, int b) { return (a + b - 1) / b; }

// ---- bf16 split helpers (RNE) ----------------------------------------------
__device__ __forceinline__ float bf2f(unsigned short s) {
    return __uint_as_float(((unsigned int)s) << 16);
}
__device__ __forceinline__ unsigned short f2bf(float x) {
    unsigned int u = __float_as_uint(x);
    return (unsigned short)((u + 0x7FFFu + ((u >> 16) & 1u)) >> 16);
}
__device__ __forceinline__ unsigned short bf_hi(float x, float& rem) {
    unsigned int u = __float_as_uint(x);
    unsigned int hi = (u + 0x7FFFu + ((u >> 16) & 1u)) & 0xFFFF0000u;
    rem = x - __uint_as_float(hi);
    return (unsigned short)(hi >> 16);
}
// split-tiled layout: elem (row r, feat k) of an NPx128 matrix lives at unit
//   panel(r>>7)*32768 + (k>>3)*1024 + (r&127)*8 + (k&7);  lo plane at +16384.

struct EdgeArgs {
    const int* adj[12];
    int E[12];
    int colOff[12];
};

// ---------------------------------------------------------------------------
// Label representation: char-CNN + relu + max over positions.
// ---------------------------------------------------------------------------
__global__ __launch_bounds__(64) void label_kernel(
    const int* __restrict__ labels, const float* __restrict__ char_embed,
    const float* __restrict__ conv_w, const float* __restrict__ conv_b,
    float* __restrict__ lr, int U)
{
    __shared__ float ch[20][16];
    __shared__ int lab[16];
    const int u = blockIdx.x, t = threadIdx.x;
    {
        const int r = t >> 4, i = t & 15;
        const int padrow[4] = {0, 1, 18, 19};
        ch[padrow[r]][i] = 0.f;
    }
    if (t < 16) lab[t] = labels[(size_t)u * 16 + t];
    float cwr[5][16];
    #pragma unroll
    for (int k = 0; k < 5; ++k)
        #pragma unroll
        for (int i = 0; i < 16; ++i)
            cwr[k][i] = conv_w[(k * 16 + i) * 64 + t];
    __syncthreads();
    for (int j = t; j < 256; j += 64)
        ch[2 + (j >> 4)][j & 15] = char_embed[(size_t)lab[j >> 4] * 16 + (j & 15)];
    __syncthreads();
    float aw[16];
    const float b = conv_b[t];
    #pragma unroll
    for (int w = 0; w < 16; ++w) aw[w] = b;
    #pragma unroll
    for (int x = 0; x < 20; ++x)
        #pragma unroll
        for (int i = 0; i < 16; ++i) {
            const float chv = ch[x][i];
            #pragma unroll
            for (int k = 0; k < 5; ++k) {
                const int w = x - k;
                if (w >= 0 && w < 16) aw[w] += chv * cwr[k][i];
            }
        }
    float m = 0.f;
    #pragma unroll
    for (int w = 0; w < 16; ++w) m = fmaxf(m, aw[w]);
    lr[(size_t)u * 64 + t] = m;
}

// ---------------------------------------------------------------------------
// h init -> split-tiled (hi+lo bf16). Pads zeroed.
// ---------------------------------------------------------------------------
__global__ void init_h_split(const int* __restrict__ idx, const float* __restrict__ lr,
                             unsigned short* __restrict__ hS, int N, int NP)
{
    const int i = blockIdx.x * blockDim.x + threadIdx.x;
    if (i >= NP * 16) return;
    const int n = i >> 4, kg = i & 15;
    const size_t u = (size_t)(n >> 7) * 32768 + (size_t)kg * 1024 + (size_t)(n & 127) * 8;
    short8 hi, lo;
    if (n < N && kg < 8) {
        const int id = idx[n];
        #pragma unroll
        for (int j = 0; j < 8; ++j) {
            const float v = lr[(size_t)id * 64 + kg * 8 + j];
            float r; hi[j] = (short)bf_hi(v, r); lo[j] = (short)f2bf(r);
        }
    } else {
        #pragma unroll
        for (int j = 0; j < 8; ++j) { hi[j] = 0; lo[j] = 0; }
    }
    *(short8*)(hS + u) = hi;
    *(short8*)(hS + u + 16384) = lo;
}

// ---------------------------------------------------------------------------
// CSR build
// ---------------------------------------------------------------------------
__global__ void hist_kernel(EdgeArgs ea, int* __restrict__ deg, int N)
{
    const int t = blockIdx.y;
    const int e = blockIdx.x * blockDim.x + threadIdx.x;
    if (e >= ea.E[t]) return;
    atomicAdd(&deg[(size_t)t * N + ea.adj[t][2 * e + 1]], 1);
}

__global__ __launch_bounds__(256) void scan_a(const int* __restrict__ deg,
                                              int* __restrict__ partial, int N, int nchunk)
{
    const int t = blockIdx.y, b = blockIdx.x;
    const int base = b * 2048;
    int s = 0;
    for (int i = threadIdx.x; i < 2048; i += 256) {
        const int g = base + i;
        if (g < N) s += deg[(size_t)t * N + g];
    }
    __shared__ int sm[256];
    sm[threadIdx.x] = s; __syncthreads();
    for (int off = 128; off > 0; off >>= 1) {
        if (threadIdx.x < off) sm[threadIdx.x] += sm[threadIdx.x + off];
        __syncthreads();
    }
    if (threadIdx.x == 0) partial[t * nchunk + b] = sm[0];
}

__global__ void scan_b(int* __restrict__ partial, int nchunk)
{
    const int t = threadIdx.x;
    if (t >= 12) return;
    int off = 0;
    for (int i = 0; i < nchunk; ++i) {
        const int s = partial[t * nchunk + i];
        partial[t * nchunk + i] = off;
        off += s;
    }
}

__global__ __launch_bounds__(256) void scan_c(const int* __restrict__ deg,
                                              const int* __restrict__ partial,
                                              int* __restrict__ rowptr, int N, int nchunk)
{
    const int t = blockIdx.y, b = blockIdx.x;
    int* rp = rowptr + (size_t)t * (N + 1);
    const int base = b * 2048;
    int v[8]; int s = 0;
    #pragma unroll
    for (int j = 0; j < 8; ++j) {
        const int g = base + threadIdx.x * 8 + j;
        v[j] = (g < N) ? deg[(size_t)t * N + g] : 0;
        s += v[j];
    }
    __shared__ int ts[256];
    ts[threadIdx.x] = s; __syncthreads();
    for (int off = 1; off < 256; off <<= 1) {
        const int val = (threadIdx.x >= off) ? ts[threadIdx.x - off] : 0;
        __syncthreads();
        ts[threadIdx.x] += val;
        __syncthreads();
    }
    int run = partial[t * nchunk + b] + (threadIdx.x ? ts[threadIdx.x - 1] : 0);
    #pragma unroll
    for (int j = 0; j < 8; ++j) {
        const int g = base + threadIdx.x * 8 + j;
        run += v[j];
        if (g < N) rp[g + 1] = run;
    }
    if (b == 0 && threadIdx.x == 0) rp[0] = 0;
}

__global__ void fill_kernel(EdgeArgs ea, const int* __restrict__ rowptr,
                            int* __restrict__ cursor, int* __restrict__ col, int N)
{
    const int t = blockIdx.y;
    const int e = blockIdx.x * blockDim.x + threadIdx.x;
    if (e >= ea.E[t]) return;
    const int s  = ea.adj[t][2 * e];
    const int tg = ea.adj[t][2 * e + 1];
    const int pos = rowptr[(size_t)t * (N + 1) + tg] + atomicAdd(&cursor[(size_t)t * N + tg], 1);
    col[ea.colOff[t] + pos] = s;
}

// ---------------------------------------------------------------------------
// Weight pre-split into fragment-tiled hi/lo bf16.
// ---------------------------------------------------------------------------
struct WSrc { const float* wmsg; const float* gk; const float* grk; const float* w1; };

__global__ void split_w_kernel(WSrc s, unsigned short* __restrict__ wb, int nmat)
{
    const int gidx = blockIdx.x * 256 + threadIdx.x;
    const int m = gidx >> 14, e = gidx & 16383;
    if (m >= nmat) return;
    const int kg = e >> 10, rem = e & 1023, c = rem >> 3, j = rem & 7;
    const int k = kg * 8 + j;
    float x;
    if (m < 72) x = s.wmsg[(size_t)m * 16384 + (size_t)k * 128 + c];
    else if (m < 108) {
        const int g = m - 72, layer = g / 6, r2 = g % 6;
        const float* base = (r2 < 3) ? s.gk : s.grk;
        const int slice = r2 % 3;
        x = base[(size_t)layer * 49152 + (size_t)k * 384 + slice * 128 + c];
    } else x = s.w1[(size_t)k * 128 + c];
    float r; const unsigned short hi = bf_hi(x, r);
    wb[(size_t)m * 32768 + e] = hi;
    wb[(size_t)m * 32768 + 16384 + e] = f2bf(r);
}

// ---------------------------------------------------------------------------
// Pipelined MFMA GEMM. A panels split into four 16KB quarters (4 kg x hi+lo),
// double-buffered in 2x16KB LDS. Steady state: MFMA on quarter s overlaps the
// in-flight global loads for quarter s+2 (issued one iter earlier); ds_write
// of s+1 + one barrier per iter. XOR bank swizzle on the kg dimension.
//   NM: B matrices per stage (1 or 2). NST: A panels (K stages). ACT:
//   0 plain (no bias), 1 bias+leaky, 2 bias+sigmoid (both outs), 3 bias+plain.
// outX may alias A panels (per-block self-overwrite; epilogue after all reads).
// ---------------------------------------------------------------------------
template<int NM, int NST, int ACT>
__global__ __launch_bounds__(256) void gemm_pipe(
    const unsigned short* __restrict__ A0, const unsigned short* __restrict__ A1,
    const unsigned short* __restrict__ B00, const unsigned short* __restrict__ B01,
    const unsigned short* __restrict__ B10, const unsigned short* __restrict__ B11,
    const float* __restrict__ bias,
    float* __restrict__ out0, float* __restrict__ out1)
{
    __shared__ unsigned short lds[2][8192];
    const int tid = threadIdx.x;
    const size_t pbase = (size_t)blockIdx.x * 32768;
    const unsigned short* Ap[2];
    Ap[0] = A0 + pbase;
    Ap[1] = A1 ? A1 + pbase : nullptr;
    const unsigned short* Bp[2][2] = {{B00, B01}, {B10, B11}};
    constexpr int S = NST * 4;

    const int wave = tid >> 6, lane = tid & 63;
    const int wr = wave >> 1, wc = wave & 1, lrow = lane & 15, lkg = lane >> 4;
    f32x4 acc[NM][4][4] = {};
    short8 r[4];

    auto ldq = [&](int s) {
        const unsigned short* __restrict__ A = Ap[s >> 2];
        const int qb = (s & 3) * 4096;
        r[0] = *(const short8*)(A + qb + tid * 8);
        r[1] = *(const short8*)(A + qb + 2048 + tid * 8);
        r[2] = *(const short8*)(A + 16384 + qb + tid * 8);
        r[3] = *(const short8*)(A + 16384 + qb + 2048 + tid * 8);
    };
    auto stq = [&](int buf) {
        unsigned short* L = lds[buf];
        #pragma unroll
        for (int j = 0; j < 4; ++j) {
            const int d = ((j >> 1) << 12) + ((j & 1) << 11) + tid * 8;
            const int sd = d ^ (((d >> 10) & 3) << 3);      // bank swizzle
            *(short8*)(L + sd) = r[j];
        }
    };
    auto mfma_q = [&](int buf, int s) {
        const unsigned short* L = lds[buf];
        const int q = s & 3;
        short8 ah[4], al[4];
        #pragma unroll
        for (int m = 0; m < 4; ++m) {
            int u = (lkg << 10) + (wr * 64 + m * 16 + lrow) * 8;
            u ^= (lkg << 3);                                 // matching swizzle
            ah[m] = *(const short8*)(L + u);
            al[m] = *(const short8*)(L + u + 4096);
        }
        #pragma unroll
        for (int t = 0; t < NM; ++t) {
            const unsigned short* __restrict__ B = Bp[s >> 2][t];
            short8 bh[4], bl[4];
            #pragma unroll
            for (int n = 0; n < 4; ++n) {
                const int ub = (q * 4 + lkg) * 1024 + (wc * 64 + n * 16 + lrow) * 8;
                bh[n] = *(const short8*)(B + ub);
                bl[n] = *(const short8*)(B + ub + 16384);
            }
            #pragma unroll
            for (int m = 0; m < 4; ++m)
                #pragma unroll
                for (int n = 0; n < 4; ++n) {
                    acc[t][m][n] = __builtin_amdgcn_mfma_f32_16x16x32_bf16(ah[m], bh[n], acc[t][m][n], 0, 0, 0);
                    acc[t][m][n] = __builtin_amdgcn_mfma_f32_16x16x32_bf16(ah[m], bl[n], acc[t][m][n], 0, 0, 0);
                    acc[t][m][n] = __builtin_amdgcn_mfma_f32_16x16x32_bf16(al[m], bh[n], acc[t][m][n], 0, 0, 0);
                }
        }
    };

    ldq(0); stq(0);
    if (S > 1) ldq(1);
    __syncthreads();
    #pragma unroll
    for (int s = 0; s < S; ++s) {
        mfma_q(s & 1, s);
        if (s + 1 < S) {
            stq((s + 1) & 1);
            if (s + 2 < S) ldq(s + 2);
            __syncthreads();
        }
    }

    const size_t rowBase = (size_t)blockIdx.x * 128;
    #pragma unroll
    for (int t = 0; t < NM; ++t) {
        float* __restrict__ op = t ? out1 : out0;
        #pragma unroll
        for (int m = 0; m < 4; ++m)
            #pragma unroll
            for (int n = 0; n < 4; ++n) {
                const int col = wc * 64 + n * 16 + lrow;
                #pragma unroll
                for (int i = 0; i < 4; ++i) {
                    const size_t rg = rowBase + wr * 64 + m * 16 + lkg * 4 + i;
                    float v = acc[t][m][n][i];
                    if (ACT != 0) v += bias[t * 128 + col];
                    if (ACT == 1) v = v > 0.f ? v : LEAKY_SLOPE * v;
                    else if (ACT == 2) v = 1.f / (1.f + __expf(-v));
                    op[rg * 128 + col] = v;
                }
            }
    }
}

// ---------------------------------------------------------------------------
// rh = R (pre-sigmoided, f32 row-major) * h  -> split-tiled, IN PLACE over R.
// Block stages its own R panel in LDS (row-swizzled), barrier, then writes.
// ---------------------------------------------------------------------------
__global__ __launch_bounds__(256) void rh_panel(const unsigned short* __restrict__ hS,
                                                float* __restrict__ R)
{
    __shared__ float ld[16384];
    const int tid = threadIdx.x;
    const size_t pf = (size_t)blockIdx.x * 16384;
    #pragma unroll
    for (int j = 0; j < 16; ++j) {
        const int idx = j * 1024 + tid * 4;
        const int row = idx >> 7, col = idx & 127;
        const float4 v = *(const float4*)(R + pf + idx);
        *(float4*)(ld + row * 128 + (col ^ ((row & 7) << 2))) = v;
    }
    __syncthreads();
    unsigned short* out = (unsigned short*)(R + pf);
    const unsigned short* hp = hS + (size_t)blockIdx.x * 32768;
    #pragma unroll
    for (int j = 0; j < 8; ++j) {
        const int u = j * 2048 + tid * 8;
        const int row = (u >> 3) & 127, kg = u >> 10;
        const short8 hh = *(const short8*)(hp + u);
        const short8 hl = *(const short8*)(hp + u + 16384);
        short8 rhi, rlo;
        #pragma unroll
        for (int q = 0; q < 8; ++q) {
            const int col = kg * 8 + q;
            const float rv = ld[row * 128 + (col ^ ((row & 7) << 2))];
            const float h = bf2f((unsigned short)hh[q]) + bf2f((unsigned short)hl[q]);
            const float x = rv * h;
            float rem; rhi[q] = (short)bf_hi(x, rem); rlo[q] = (short)f2bf(rem);
        }
        *(short8*)(out + u) = rhi;
        *(short8*)(out + u + 16384) = rlo;
    }
}

// ---------------------------------------------------------------------------
// Gathers. 32 threads/node, float4 rows.
// ---------------------------------------------------------------------------
__global__ __launch_bounds__(256) void gather_csr(
    const int* __restrict__ rowptr, const int* __restrict__ col,
    const float* __restrict__ M, float* __restrict__ agg, int N, int accum)
{
    const int i = blockIdx.x * blockDim.x + threadIdx.x;
    const int n = i >> 5, q = i & 31;
    if (n >= N) return;
    float4 acc;
    if (accum) acc = *reinterpret_cast<const float4*>(agg + (size_t)n * 128 + (q << 2));
    else       acc = make_float4(0.f, 0.f, 0.f, 0.f);
    for (int s = rowptr[n]; s < rowptr[n + 1]; ++s) {
        const float4 v = *reinterpret_cast<const float4*>(M + (size_t)col[s] * 128 + (q << 2));
        acc.x += v.x; acc.y += v.y; acc.z += v.z; acc.w += v.w;
    }
    *reinterpret_cast<float4*>(agg + (size_t)n * 128 + (q << 2)) = acc;
}

__global__ __launch_bounds__(256) void gather2_csr(
    const int* __restrict__ rp0, const int* __restrict__ c0, const float* __restrict__ M0,
    const int* __restrict__ rp1, const int* __restrict__ c1, const float* __restrict__ M1,
    float* __restrict__ agg, int N, int accum)
{
    const int i = blockIdx.x * blockDim.x + threadIdx.x;
    const int n = i >> 5, q = i & 31;
    if (n >= N) return;
    float4 acc;
    if (accum) acc = *reinterpret_cast<const float4*>(agg + (size_t)n * 128 + (q << 2));
    else       acc = make_float4(0.f, 0.f, 0.f, 0.f);
    for (int s = rp0[n]; s < rp0[n + 1]; ++s) {
        const float4 v = *reinterpret_cast<const float4*>(M0 + (size_t)c0[s] * 128 + (q << 2));
        acc.x += v.x; acc.y += v.y; acc.z += v.z; acc.w += v.w;
    }
    for (int s = rp1[n]; s < rp1[n + 1]; ++s) {
        const float4 v = *reinterpret_cast<const float4*>(M1 + (size_t)c1[s] * 128 + (q << 2));
        acc.x += v.x; acc.y += v.y; acc.z += v.z; acc.w += v.w;
    }
    *reinterpret_cast<float4*>(agg + (size_t)n * 128 + (q << 2)) = acc;
}

// Final gather of the layer: add last etype, emit agg directly split-tiled.
__global__ __launch_bounds__(256) void gather_split_csr(
    const int* __restrict__ rp, const int* __restrict__ cl, const float* __restrict__ M,
    const float* __restrict__ agg, unsigned short* __restrict__ aT, int N, int NP)
{
    const int i = blockIdx.x * blockDim.x + threadIdx.x;
    const int n = i >> 5, q = i & 31;
    if (n >= NP) return;
    float4 a = make_float4(0.f, 0.f, 0.f, 0.f);
    if (n < N) {
        a = *reinterpret_cast<const float4*>(agg + (size_t)n * 128 + (q << 2));
        for (int s = rp[n]; s < rp[n + 1]; ++s) {
            const float4 v = *reinterpret_cast<const float4*>(M + (size_t)cl[s] * 128 + (q << 2));
            a.x += v.x; a.y += v.y; a.z += v.z; a.w += v.w;
        }
    }
    const size_t u = (size_t)(n >> 7) * 32768 + (size_t)(q >> 1) * 1024
                   + (size_t)(n & 127) * 8 + (q & 1) * 4;
    const float vv[4] = {a.x, a.y, a.z, a.w};
    short4v hi, lo;
    #pragma unroll
    for (int j = 0; j < 4; ++j) {
        float r; hi[j] = (short)bf_hi(vv[j], r); lo[j] = (short)f2bf(r);
    }
    *(short4v*)(aT + u) = hi;
    *(short4v*)(aT + u + 16384) = lo;
}

// ---------------------------------------------------------------------------
// GRU final: h = Z*h + (1-Z)*tanh(G); h kept split-tiled (in-place).
// ---------------------------------------------------------------------------
__global__ void gru_ew2_split(const float* __restrict__ Z, const float* __restrict__ G,
                              unsigned short* __restrict__ hS, int N)
{
    const int i = blockIdx.x * blockDim.x + threadIdx.x;
    if (i >= N * 16) return;
    const int n = i >> 4, kg = i & 15;
    const size_t u = (size_t)(n >> 7) * 32768 + (size_t)kg * 1024 + (size_t)(n & 127) * 8;
    const short8 hi = *(const short8*)(hS + u);
    const short8 lo = *(const short8*)(hS + u + 16384);
    const size_t ro = (size_t)n * 128 + kg * 8;
    short8 nhi, nlo;
    #pragma unroll
    for (int j = 0; j < 8; ++j) {
        const float h = bf2f((unsigned short)hi[j]) + bf2f((unsigned short)lo[j]);
        const float z = Z[ro + j];
        const float hn = z * h + (1.f - z) * tanhf(G[ro + j]);
        float r; nhi[j] = (short)bf_hi(hn, r); nlo[j] = (short)f2bf(r);
    }
    *(short8*)(hS + u) = nhi;
    *(short8*)(hS + u + 16384) = nlo;
}

// ---------------------------------------------------------------------------
// Final: thread-per-node; wave-uniform graph atomic (n2g sorted).
// ---------------------------------------------------------------------------
__global__ __launch_bounds__(256) void final_kernel(
    const unsigned short* __restrict__ hS, const float* __restrict__ V1,
    const int* __restrict__ n2g,
    const float* __restrict__ w2, const float* __restrict__ b2,
    const float* __restrict__ w3, const float* __restrict__ b3,
    const float* __restrict__ w4, const float* __restrict__ b4,
    const float* __restrict__ score_w, const float* __restrict__ score_b,
    float* __restrict__ out, int N)
{
    const int n = blockIdx.x * blockDim.x + threadIdx.x;
    const int nc = n < N ? n : N - 1;
    const int g = n2g[nc];

    float sp = score_b[0];
    #pragma unroll 4
    for (int kg = 0; kg < 16; ++kg) {
        const size_t u = (size_t)(nc >> 7) * 32768 + (size_t)kg * 1024 + (size_t)(nc & 127) * 8;
        const short8 hh = *(const short8*)(hS + u);
        const short8 hl = *(const short8*)(hS + u + 16384);
        #pragma unroll
        for (int j = 0; j < 8; ++j)
            sp += (bf2f((unsigned short)hh[j]) + bf2f((unsigned short)hl[j])) * score_w[kg * 8 + j];
    }

    float V2[32];
    #pragma unroll
    for (int j = 0; j < 32; ++j) V2[j] = b2[j];
    #pragma unroll 2
    for (int k = 0; k < 128; k += 4) {
        const float4 v1 = *reinterpret_cast<const float4*>(V1 + (size_t)nc * 128 + k);
        const float vv[4] = {v1.x, v1.y, v1.z, v1.w};
        #pragma unroll
        for (int kk = 0; kk < 4; ++kk)
            #pragma unroll
            for (int j = 0; j < 32; ++j)
                V2[j] += vv[kk] * w2[(k + kk) * 32 + j];
    }
    #pragma unroll
    for (int j = 0; j < 32; ++j) { const float x = V2[j]; V2[j] = x > 0.f ? x : LEAKY_SLOPE * x; }

    float V3[8];
    #pragma unroll
    for (int j = 0; j < 8; ++j) V3[j] = b3[j];
    #pragma unroll
    for (int k = 0; k < 32; ++k)
        #pragma unroll
        for (int j = 0; j < 8; ++j) V3[j] += V2[k] * w3[k * 8 + j];
    #pragma unroll
    for (int j = 0; j < 8; ++j) { const float x = V3[j]; V3[j] = x > 0.f ? x : LEAKY_SLOPE * x; }

    float o4 = b4[0];
    #pragma unroll
    for (int j = 0; j < 8; ++j) o4 += V3[j] * w4[j];

    const float sc = 1.f / (1.f + __expf(-sp));
    float val = (n < N) ? sc * o4 : 0.f;

    const int g0 = __shfl(g, 0, 64);
    if (__all(g == g0)) {
        #pragma unroll
        for (int d = 32; d > 0; d >>= 1) val += __shfl_xor(val, d, 64);
        if ((threadIdx.x & 63) == 0) unsafeAtomicAdd(out + g0, val);
    } else {
        if (n < N) unsafeAtomicAdd(out + g, val);
    }
}

// ---------------------------------------------------------------------------
extern "C" void kernel_launch(void* const* d_in, const int* in_sizes, int n_in,
                              void* d_out, int out_size, void* d_ws, size_t ws_size,
                              hipStream_t stream)
{
    (void)n_in;
    const int* labels   = (const int*)d_in[1];
    const int* nidx     = (const int*)d_in[2];
    const int* n2g      = (const int*)d_in[3];
    EdgeArgs ea;
    int Emax = 0, Etot = 0;
    for (int t = 0; t < 12; ++t) {
        ea.adj[t] = (const int*)d_in[5 + t];
        ea.E[t] = in_sizes[5 + t] / 2;
        ea.colOff[t] = Etot;
        Etot += ea.E[t];
        if (ea.E[t] > Emax) Emax = ea.E[t];
    }
    const float* char_embed = (const float*)d_in[17];
    const float* conv_w     = (const float*)d_in[18];
    const float* conv_b     = (const float*)d_in[19];
    const float* W_msg      = (const float*)d_in[20];
    const float* gru_k      = (const float*)d_in[21];
    const float* gru_rk     = (const float*)d_in[22];
    const float* gru_b      = (const float*)d_in[23];
    const float* score_w    = (const float*)d_in[24];
    const float* score_b    = (const float*)d_in[25];
    const float* w1 = (const float*)d_in[26];
    const float* b1 = (const float*)d_in[27];
    const float* w2 = (const float*)d_in[28];
    const float* b2 = (const float*)d_in[29];
    const float* w3 = (const float*)d_in[30];
    const float* b3 = (const float*)d_in[31];
    const float* w4 = (const float*)d_in[32];
    const float* b4 = (const float*)d_in[33];

    const int N = in_sizes[2];
    const int U = in_sizes[1] / 16;
    const int G = out_size;
    float* out = (float*)d_out;

    const int NPB = cdiv(N, 128);
    const int NP  = NPB * 128;
    const int NCHUNK = cdiv(N, 2048);
    const int NMAT = 109;

    // ---- workspace ----
    float* ws = (float*)d_ws;
    size_t o = 0;
    float* lr   = ws + o; o += (size_t)U * 64;
    float* hSf  = ws + o; o += (size_t)NP * 128;   // h split-tiled
    float* Mf   = ws + o; o += (size_t)NP * 128;   // M0 f32 / aT split / G f32
    float* aggf = ws + o; o += (size_t)NP * 128;   // agg f32 -> Z f32
    float* rhf  = ws + o; o += (size_t)NP * 128;   // M1 f32 / R f32 -> rh split
    float* wbf  = ws + o; o += (size_t)NMAT * 16384;
    int* rowptr = (int*)(ws + o);
    int* colarr = rowptr + (size_t)12 * (N + 1);
    const size_t total_bytes = o * sizeof(float)
        + ((size_t)12 * (N + 1) + (size_t)Etot) * sizeof(int);
    if (total_bytes > ws_size) return;

    unsigned short* hS  = (unsigned short*)hSf;
    unsigned short* aT  = (unsigned short*)Mf;
    unsigned short* rhS = (unsigned short*)rhf;
    unsigned short* wb  = (unsigned short*)wbf;

    // CSR temporaries inside M region (free until first msg GEMM)
    int* deg     = (int*)Mf;
    int* cursor  = deg + (size_t)12 * N;
    int* partial = cursor + (size_t)12 * N;

    hipMemsetAsync(d_out, 0, (size_t)G * sizeof(float), stream);
    hipMemsetAsync(deg, 0, ((size_t)24 * N + 12 * NCHUNK) * sizeof(int), stream);

    {
        const dim3 ge(cdiv(Emax, 256), 12);
        const dim3 gs(NCHUNK, 12);
        hist_kernel<<<ge, 256, 0, stream>>>(ea, deg, N);
        scan_a<<<gs, 256, 0, stream>>>(deg, partial, N, NCHUNK);
        scan_b<<<1, 64, 0, stream>>>(partial, NCHUNK);
        scan_c<<<gs, 256, 0, stream>>>(deg, partial, rowptr, N, NCHUNK);
        fill_kernel<<<ge, 256, 0, stream>>>(ea, rowptr, cursor, colarr, N);
    }

    WSrc wsrc{W_msg, gru_k, gru_rk, w1};
    split_w_kernel<<<cdiv(NMAT * 16384, 256), 256, 0, stream>>>(wsrc, wb, NMAT);
    label_kernel<<<U, 64, 0, stream>>>(labels, char_embed, conv_w, conv_b, lr, U);
    init_h_split<<<cdiv(NP * 16, 256), 256, 0, stream>>>(nidx, lr, hS, N, NP);

    const int gatherBlocks = cdiv(N * 32, 256);
    const int gatherBlocksNP = cdiv(NP * 32, 256);
    const int ewBlocks = cdiv(N * 16, 256);
    auto rp  = [&](int t) { return rowptr + (size_t)t * (N + 1); };
    auto cp  = [&](int t) { return colarr + ea.colOff[t]; };
    auto wbm = [&](int m) { return wb + (size_t)m * 32768; };

    for (int layer = 0; layer < 6; ++layer) {
        const float* bl = gru_b + (size_t)layer * 384;
        const int mk = 72 + layer * 6;
        // message passing: 5 pipelined pairs + 2 singles (last emits split agg)
        for (int p = 0; p < 5; ++p) {
            const int t0 = 2 * p, t1 = 2 * p + 1;
            gemm_pipe<2, 1, 0><<<NPB, 256, 0, stream>>>(
                hS, nullptr, wbm(layer * 12 + t0), wbm(layer * 12 + t1),
                nullptr, nullptr, nullptr, Mf, rhf);
            gather2_csr<<<gatherBlocks, 256, 0, stream>>>(rp(t0), cp(t0), Mf,
                                                          rp(t1), cp(t1), rhf, aggf, N, p > 0);
        }
        gemm_pipe<1, 1, 0><<<NPB, 256, 0, stream>>>(
            hS, nullptr, wbm(layer * 12 + 10), nullptr, nullptr, nullptr, nullptr, Mf, nullptr);
        gather_csr<<<gatherBlocks, 256, 0, stream>>>(rp(10), cp(10), Mf, aggf, N, 1);
        gemm_pipe<1, 1, 0><<<NPB, 256, 0, stream>>>(
            hS, nullptr, wbm(layer * 12 + 11), nullptr, nullptr, nullptr, nullptr, rhf, nullptr);
        gather_split_csr<<<gatherBlocksNP, 256, 0, stream>>>(rp(11), cp(11), rhf, aggf, aT, N, NP);
        // Z = sigmoid(agg@k0 + h@rk0 + bz) -> aggf; R = sigmoid(agg@k1 + h@rk1 + br) -> rhf
        gemm_pipe<2, 2, 2><<<NPB, 256, 0, stream>>>(
            aT, hS, wbm(mk + 0), wbm(mk + 1), wbm(mk + 3), wbm(mk + 4), bl, aggf, rhf);
        // rh = R * h -> split-tiled, in place over rhf
        rh_panel<<<NPB, 256, 0, stream>>>(hS, rhf);
        // G = agg@k2 + rh@rk2 + bg -> Mf
        gemm_pipe<1, 2, 3><<<NPB, 256, 0, stream>>>(
            aT, rhS, wbm(mk + 2), nullptr, wbm(mk + 5), nullptr, bl + 256, Mf, nullptr);
        // h = Z*h + (1-Z)*tanh(G)
        gru_ew2_split<<<ewBlocks, 256, 0, stream>>>(aggf, Mf, hS, N);
    }
    // V1 = leaky(h @ w1 + b1)
    gemm_pipe<1, 1, 1><<<NPB, 256, 0, stream>>>(
        hS, nullptr, wbm(108), nullptr, nullptr, nullptr, b1, Mf, nullptr);
    final_kernel<<<cdiv(N, 256), 256, 0, stream>>>(hS, Mf, n2g, w2, b2, w3, b3, w4, b4,
                                                   score_w, score_b, out, N);
}